// Round 9
// baseline (562.261 us; speedup 1.0000x reference)
//
#include <hip/hip_runtime.h>

// Problem constants
constexpr int kB = 8;
constexpr int kN = 2046;
constexpr int kC = 2048;   // kN + 2
constexpr int kD = 128;
constexpr int kJ = 128;
constexpr int kL = 2;

typedef short bfrag8 __attribute__((ext_vector_type(8)));
typedef float f32x4 __attribute__((ext_vector_type(4)));

// ---------- bf16 helpers ----------
__device__ __forceinline__ float bf2f(unsigned short h) {
  union { unsigned u; float f; } x; x.u = ((unsigned)h) << 16; return x.f;
}
__device__ __forceinline__ unsigned short f2bf(float f) {
  union { float f; unsigned u; } x; x.f = f;
  unsigned u = x.u;
  if ((u & 0x7fffffffu) > 0x7f800000u) return (unsigned short)((u >> 16) | 0x40);
  return (unsigned short)((u + 0x7fffu + ((u >> 16) & 1u)) >> 16);
}
__device__ __forceinline__ unsigned short f2bf_fast(float f) {  // finite inputs
  union { float f; unsigned u; } x; x.f = f;
  return (unsigned short)((x.u + 0x7fffu + ((x.u >> 16) & 1u)) >> 16);
}
__device__ __forceinline__ void split2(float x, unsigned short& h, unsigned short& l) {
  unsigned short hh = f2bf_fast(x);
  h = hh;
  l = f2bf_fast(x - bf2f(hh));
}

// ---------- raw input pointers ----------
struct Raw {
  const void *ops, *mask;
  const int *rel, *bidx, *eidx;
  const void *ibw, *ibb, *iew, *ieb;       // init begin/end proj
  const void *bbw, *bbb, *bew, *beb;       // per-layer begin/end proj
  const void *sw, *sb;                     // seq_mix
  const void *aw, *ab;                     // attn_w
  const void *scw, *scb;                   // score
  const void *aow, *aob;                   // attn_out
  const void *mw, *mb;                     // mix
};

__device__ __forceinline__ float rp(const void* p, size_t i, bool bf) {
  return bf ? bf2f(((const unsigned short*)p)[i]) : ((const float*)p)[i];
}

// per-wave dtype sniff over first 1024 words of operation_features
__device__ __forceinline__ bool sniff(const Raw& r) {
  const unsigned* x = (const unsigned*)r.ops;
  int lane = (int)(threadIdx.x & 63);
  int hits = 0;
  #pragma unroll
  for (int q = 0; q < 16; ++q) {
    unsigned w = x[q * 64 + lane];
    unsigned e0 = (w >> 7) & 0xFFu;
    hits += (e0 == 0u || (e0 >= 96u && e0 <= 134u)) ? 1 : 0;
  }
  #pragma unroll
  for (int o = 1; o < 64; o <<= 1) hits += __shfl_xor(hits, o);
  return hits >= 512;
}

// ---------- workspace layout (float offsets) ----------
constexpr size_t OF_FEATS = 0;                       // 2097152
constexpr size_t OF_SEQ   = 2097152;
constexpr size_t OF_ATTN  = 4194304;
constexpr size_t OF_V     = 6291456;                 // VtF (1M floats) + bits (1M floats)
constexpr size_t OF_SQ    = 8388608;
constexpr size_t OF_SK    = 8404992;
constexpr size_t OF_U     = 8421376;
constexpr size_t OF_PART  = 8422400;
constexpr size_t OF_BMIX  = 8423424;
constexpr size_t OF_WT    = 8423680;                 // ushort arena

// Wt arena (ushort offsets), per-layer stride. Fragment layout:
// frag(kc, nt, lane, e): element (n = nt*16 + (lane&15), k = kc*32 + (lane>>4)*8 + e)
constexpr int WT_SEQH = 0;        // K=384
constexpr int WT_SEQL = 49152;
constexpr int WT_VH   = 98304;    // K=128
constexpr int WT_VL   = 114688;
constexpr int WT_MIXH = 131072;   // K=256
constexpr int WT_MIXL = 163840;
constexpr int WT_LS   = 196608;

// prep role boundaries (mask removed; bits-zero added)
constexpr int RP_CAST = 4092;
constexpr int RP_WT   = RP_CAST + 640;   // 4732
constexpr int RP_WF   = RP_WT + 258;     // 4990
constexpr int RP_UV   = RP_WF + 2;       // 4992
constexpr int RP_BE   = RP_UV + 16;      // 5008
constexpr int RP_ZB   = RP_BE + 256;     // 5264  (zero bits, 4 MB)
constexpr int RP_TOT  = RP_ZB + 1;       // 5265  (zero part)

// ---------- MFMA helper ----------
__device__ __forceinline__ f32x4 mfma16(bfrag8 a, bfrag8 b, f32x4 c) {
  return __builtin_amdgcn_mfma_f32_16x16x32_bf16(a, b, c, 0, 0, 0);
}

// ---------- K0a: flat-streaming mask -> bits (atomicOr; bits pre-zeroed by k_prep) ----------
__global__ __launch_bounds__(256) void k_mask(Raw r, unsigned* __restrict__ bits32) {
  bool bf = sniff(r);
  unsigned idx = blockIdx.x * 256 + threadIdx.x;
  constexpr unsigned NT = (unsigned)((size_t)kB * kN * kN / 8);   // 4,186,116
  if (idx >= NT) return;
  unsigned e0 = idx * 8u;
  bool nz[8];
  if (bf) {
    uint4 v = ((const uint4*)r.mask)[idx];
    unsigned u[4] = {v.x, v.y, v.z, v.w};
    #pragma unroll
    for (int k = 0; k < 8; ++k) {
      unsigned h = (k & 1) ? (u[k >> 1] >> 16) : (u[k >> 1] & 0xFFFFu);
      nz[k] = (h != 0u);
    }
  } else {
    uint4 v0 = ((const uint4*)r.mask)[idx * 2];
    uint4 v1 = ((const uint4*)r.mask)[idx * 2 + 1];
    unsigned u[8] = {v0.x, v0.y, v0.z, v0.w, v1.x, v1.y, v1.z, v1.w};
    #pragma unroll
    for (int k = 0; k < 8; ++k) nz[k] = (u[k] != 0u);
  }
  constexpr unsigned NN = (unsigned)kN * (unsigned)kN;   // 4,186,116
  unsigned bq  = e0 / NN;
  unsigned rem = e0 - bq * NN;
  unsigned row = rem / (unsigned)kN;
  unsigned col = rem - row * (unsigned)kN;
  size_t  curw = ((size_t)bq * kC + row) * 64 + (col >> 5);
  unsigned bit = col & 31u;
  unsigned accm = 0;
  #pragma unroll
  for (int k = 0; k < 8; ++k) {
    if (nz[k]) accm |= (1u << bit);
    // advance
    ++col; ++bit;
    size_t nextw = curw;
    if (col == (unsigned)kN) {
      col = 0; ++row;
      if (row == (unsigned)kN) { row = 0; ++bq; }
      nextw = ((size_t)bq * kC + row) * 64;
      bit = 0;
    } else if (bit == 32u) {
      nextw = curw + 1; bit = 0;
    }
    if (nextw != curw) {
      if (accm) atomicOr(&bits32[curw], accm);
      accm = 0; curw = nextw;
    }
  }
  if (accm) atomicOr(&bits32[curw], accm);
}

// ---------- K0b: prep (all non-mask roles) ----------
__global__ __launch_bounds__(256) void k_prep(Raw r, float* __restrict__ feats,
                                              unsigned* __restrict__ bits32,
                                              unsigned short* __restrict__ wt,
                                              float* __restrict__ bmix,
                                              float* __restrict__ u2,
                                              float* __restrict__ part) {
  __shared__ __align__(16) char smem[4096];
  int bid = blockIdx.x, t = threadIdx.x;
  bool bf = sniff(r);

  if (bid < RP_CAST) {
    // cast ops -> feats rows 0..N-1
    int idx = bid * 256 + t;
    int elem = idx * 2;
    int b = elem / (kN * kD);
    int rr = elem - b * (kN * kD);
    float2 f;
    if (bf) {
      unsigned u = ((const unsigned*)r.ops)[idx];
      f.x = bf2f((unsigned short)(u & 0xffffu));
      f.y = bf2f((unsigned short)(u >> 16));
    } else {
      f = ((const float2*)r.ops)[idx];
    }
    *(float2*)(feats + (size_t)b * kC * kD + rr) = f;
  } else if (bid < RP_WT) {
    // transpose+split weights into fragment layout
    int idx = (bid - RP_CAST) * 256 + t;   // < 163840
    int l = idx / 81920;
    int rr = idx - l * 81920;
    const void* src; size_t si; int dH, dL, k, n;
    if (rr < 49152) {
      k = rr >> 7; n = rr & 127;
      src = r.sw; si = (size_t)l * 49152 + (size_t)k * 128 + n;
      dH = l * WT_LS + WT_SEQH; dL = l * WT_LS + WT_SEQL;
    } else if (rr < 65536) {
      int e = rr - 49152; k = e >> 7; n = e & 127;
      src = r.aw; si = (size_t)l * 49152 + (size_t)k * 384 + 256 + n;
      dH = l * WT_LS + WT_VH; dL = l * WT_LS + WT_VL;
    } else {
      int e = rr - 65536; k = e >> 7; n = e & 127;
      src = r.mw; si = (size_t)l * 32768 + (size_t)k * 128 + n;
      dH = l * WT_LS + WT_MIXH; dL = l * WT_LS + WT_MIXL;
    }
    float v = rp(src, si, bf);
    unsigned short h, lo;
    split2(v, h, lo);
    int kc = k >> 5, q = (k >> 3) & 3, e8 = k & 7;
    int fa = ((kc * 8 + (n >> 4)) * 64 + (q * 16 + (n & 15))) * 8 + e8;
    wt[dH + fa] = h;
    wt[dL + fa] = lo;
  } else if (bid < RP_WF) {
    // fuse ao_w @ mix_bot -> mix fragments k in [128,256)
    int rb = bid - RP_WT;
    int l = rb / 129, d1 = rb - l * 129;
    if (t < 128) {
      int d = t;
      size_t mixbot = (size_t)l * 32768 + 16384;
      if (d1 < 128) {
        float acc = 0.f;
        for (int d2 = 0; d2 < kD; ++d2)
          acc += rp(r.aow, (size_t)l * 16384 + (size_t)d1 * 128 + d2, bf)
               * rp(r.mw, mixbot + (size_t)d2 * 128 + d, bf);
        unsigned short h, lo;
        split2(acc, h, lo);
        int k = 128 + d1;
        int kc = k >> 5, q = (k >> 3) & 3, e8 = k & 7;
        int fa = ((kc * 8 + (d >> 4)) * 64 + (q * 16 + (d & 15))) * 8 + e8;
        wt[l * WT_LS + WT_MIXH + fa] = h;
        wt[l * WT_LS + WT_MIXL + fa] = lo;
      } else {
        float acc = rp(r.mb, (size_t)l * 128 + d, bf);
        for (int d2 = 0; d2 < kD; ++d2)
          acc += rp(r.aob, (size_t)l * 128 + d2, bf)
               * rp(r.mw, mixbot + (size_t)d2 * 128 + d, bf);
        bmix[(size_t)l * kD + d] = acc;
      }
    }
  } else if (bid < RP_UV) {
    // u-vectors
    int l = bid - RP_WF;
    float* swm = (float*)smem;
    float* red = (float*)smem + 256;
    if (t < 128) {
      swm[t]       = rp(r.scw, (size_t)l * 256 + t, bf);
      swm[128 + t] = rp(r.scw, (size_t)l * 256 + 128 + t, bf);
    }
    __syncthreads();
    if (t < 128) {
      int k = t;
      size_t base = (size_t)l * 49152 + (size_t)k * 384;
      float uq = 0.f, uk = 0.f;
      for (int d2 = 0; d2 < kD; ++d2) {
        uq += rp(r.aw, base + d2, bf) * swm[d2];
        uk += rp(r.aw, base + 128 + d2, bf) * swm[128 + d2];
      }
      float* u = u2 + (size_t)l * 272;
      u[k] = uq; u[128 + k] = uk;
      red[k] = rp(r.ab, (size_t)l * 384 + k, bf) * swm[k]
             + rp(r.ab, (size_t)l * 384 + 128 + k, bf) * swm[128 + k];
    }
    __syncthreads();
    if (t == 0) {
      float s = rp(r.scb, l, bf);
      for (int i = 0; i < 128; ++i) s += red[i];
      u2[(size_t)l * 272 + 256] = s;
    }
  } else if (bid < RP_BE) {
    // init begin/end
    int rb = bid - RP_UV;
    int b = rb >> 1, sel = rb & 1;
    float* msh = (float*)smem;
    const int* idx = (sel ? r.eidx : r.bidx) + b * kJ;
    const void* wv = sel ? r.iew : r.ibw;
    const void* bb = sel ? r.ieb : r.ibb;
    if (t < 128) {
      int d = t;
      float acc = 0.f;
      for (int j = 0; j < kJ; ++j)
        acc += rp(r.ops, ((size_t)b * kN + idx[j]) * kD + d, bf);
      msh[d] = acc * (1.0f / kJ);
    }
    __syncthreads();
    if (t < 128) {
      int d = t;
      float o = rp(bb, d, bf);
      for (int k = 0; k < kD; ++k) o += msh[k] * rp(wv, (size_t)k * kD + d, bf);
      feats[(size_t)b * kC * kD + (size_t)(kN + sel) * kD + d] = o;
    }
  } else if (bid < RP_ZB) {
    // zero bits (4 MB): 256 blocks x 1024 uint4
    int rb = bid - RP_BE;
    uint4 z = {0u, 0u, 0u, 0u};
    uint4* dst = (uint4*)bits32 + (size_t)rb * 1024;
    #pragma unroll
    for (int q = 0; q < 4; ++q) dst[q * 256 + t] = z;
  } else {
    #pragma unroll
    for (int q = 0; q < 4; ++q) part[q * 256 + t] = 0.f;
  }
}

// ---------- K1: stage1 — seq GEMM + vproj GEMM + layer begin/end ----------
__global__ __launch_bounds__(256) void k_stage1(Raw r, int l,
    const float* __restrict__ feats, const unsigned short* __restrict__ wt,
    const float* __restrict__ u2, float* __restrict__ seq,
    unsigned short* __restrict__ Vt, float* __restrict__ sq, float* __restrict__ sk)
{
  __shared__ __align__(16) char smem[21504];
  unsigned short (*Ah)[64 * 40] = (unsigned short(*)[64 * 40])smem;
  unsigned short (*Al)[64 * 40] = (unsigned short(*)[64 * 40])(smem + 10240);
  float* su = (float*)(smem + 20480);
  int bid = blockIdx.x, t = threadIdx.x;
  int lane = t & 63, w = t >> 6, m = lane & 15, quad = lane >> 4;
  bool bf = sniff(r);
  const unsigned short* wl = wt + (size_t)l * WT_LS;

  if (bid < 512) {
    bool isv = bid >= 256;
    int rb = isv ? bid - 256 : bid;
    int gr0 = rb * 64;
    int b = gr0 >> 11, r0 = gr0 & 2047;
    int arow = t >> 2, kq = (t & 3) * 8;
    int nl = r0 + arow;
    const float* fb = feats + (size_t)b * kC * kD;
    const float *s0, *s1, *s2;
    if (!isv) {
      int nr = (nl <= kN - 1) ? nl : (kN - 1);
      const int* rel = r.rel + ((size_t)b * kN + nr) * 2;
      int rpd = rel[0], rsc = rel[1];
      int p = (rpd < 0) ? kN : rpd;
      int s = (rsc < 0) ? (kN + 1) : rsc;
      s0 = fb + (size_t)nl * kD;
      s1 = fb + (size_t)p * kD;
      s2 = fb + (size_t)s * kD;
    } else {
      s0 = fb + (size_t)nl * kD; s1 = s0; s2 = s0;
      su[t] = u2[(size_t)l * 272 + t];
    }
    const int K = isv ? 128 : 384;
    const unsigned short* wth = isv ? (wl + WT_VH) : (wl + WT_SEQH);
    const unsigned short* wtl = isv ? (wl + WT_VL) : (wl + WT_SEQL);
    const unsigned short* pbh = wth + (size_t)(w * 2) * 512 + lane * 8;
    const unsigned short* pbl = wtl + (size_t)(w * 2) * 512 + lane * 8;
    float pq = 0.f, pk2 = 0.f;

    auto build = [&](int kb, int buf) {
      int kg = kb + kq;
      const float* sp;
      if (!isv) sp = (kg < 128) ? (s0 + kg) : (kg < 256) ? (s1 + kg - 128) : (s2 + kg - 256);
      else      sp = s0 + kg;
      float4 xa = *(const float4*)sp;
      float4 xb = *(const float4*)(sp + 4);
      if (isv) {
        pq  += xa.x * su[kg]     + xa.y * su[kg + 1] + xa.z * su[kg + 2] + xa.w * su[kg + 3]
             + xb.x * su[kg + 4] + xb.y * su[kg + 5] + xb.z * su[kg + 6] + xb.w * su[kg + 7];
        pk2 += xa.x * su[128 + kg]     + xa.y * su[128 + kg + 1] + xa.z * su[128 + kg + 2] + xa.w * su[128 + kg + 3]
             + xb.x * su[128 + kg + 4] + xb.y * su[128 + kg + 5] + xb.z * su[128 + kg + 6] + xb.w * su[128 + kg + 7];
      }
      unsigned short h[8], lo[8];
      split2(xa.x, h[0], lo[0]); split2(xa.y, h[1], lo[1]);
      split2(xa.z, h[2], lo[2]); split2(xa.w, h[3], lo[3]);
      split2(xb.x, h[4], lo[4]); split2(xb.y, h[5], lo[5]);
      split2(xb.z, h[6], lo[6]); split2(xb.w, h[7], lo[7]);
      uint4 ph, pl;
      ph.x = h[0] | ((unsigned)h[1] << 16);  ph.y = h[2] | ((unsigned)h[3] << 16);
      ph.z = h[4] | ((unsigned)h[5] << 16);  ph.w = h[6] | ((unsigned)h[7] << 16);
      pl.x = lo[0] | ((unsigned)lo[1] << 16); pl.y = lo[2] | ((unsigned)lo[3] << 16);
      pl.z = lo[4] | ((unsigned)lo[5] << 16); pl.w = lo[6] | ((unsigned)lo[7] << 16);
      *(uint4*)&Ah[buf][arow * 40 + kq] = ph;
      *(uint4*)&Al[buf][arow * 40 + kq] = pl;
    };

    f32x4 acc[4][2];
    #pragma unroll
    for (int mi = 0; mi < 4; ++mi) { acc[mi][0] = {0.f,0.f,0.f,0.f}; acc[mi][1] = {0.f,0.f,0.f,0.f}; }

    __syncthreads();   // su visible
    build(0, 0);
    __syncthreads();
    for (int kb = 0; kb < K; kb += 32) {
      int cur = (kb >> 5) & 1;
      int kc = kb >> 5;
      bfrag8 bh0 = *(const bfrag8*)(pbh + (size_t)kc * 4096);
      bfrag8 bh1 = *(const bfrag8*)(pbh + (size_t)kc * 4096 + 512);
      bfrag8 bl0 = {}, bl1 = {};
      if (!bf) {
        bl0 = *(const bfrag8*)(pbl + (size_t)kc * 4096);
        bl1 = *(const bfrag8*)(pbl + (size_t)kc * 4096 + 512);
      }
      if (kb + 32 < K) build(kb + 32, cur ^ 1);
      #pragma unroll
      for (int mi = 0; mi < 4; ++mi) {
        bfrag8 ah = *(const bfrag8*)&Ah[cur][(mi * 16 + m) * 40 + quad * 8];
        bfrag8 al = *(const bfrag8*)&Al[cur][(mi * 16 + m) * 40 + quad * 8];
        acc[mi][0] = mfma16(ah, bh0, acc[mi][0]);
        acc[mi][0] = mfma16(al, bh0, acc[mi][0]);
        acc[mi][1] = mfma16(ah, bh1, acc[mi][1]);
        acc[mi][1] = mfma16(al, bh1, acc[mi][1]);
        if (!bf) {
          acc[mi][0] = mfma16(ah, bl0, acc[mi][0]);
          acc[mi][1] = mfma16(ah, bl1, acc[mi][1]);
        }
      }
      __syncthreads();
    }

    int n0 = w * 32 + m;
    if (!isv) {
      float bv0 = rp(r.sb, (size_t)l * 128 + n0, bf);
      float bv1 = rp(r.sb, (size_t)l * 128 + n0 + 16, bf);
      #pragma unroll
      for (int mi = 0; mi < 4; ++mi)
        #pragma unroll
        for (int reg = 0; reg < 4; ++reg) {
          int ra = r0 + mi * 16 + quad * 4 + reg;
          if (ra < kN) {
            seq[((size_t)b * kC + ra) * kD + n0]      = acc[mi][0][reg] + bv0;
            seq[((size_t)b * kC + ra) * kD + n0 + 16] = acc[mi][1][reg] + bv1;
          }
        }
    } else {
      float bv0 = rp(r.ab, (size_t)l * 384 + 256 + n0, bf);
      float bv1 = rp(r.ab, (size_t)l * 384 + 256 + n0 + 16, bf);
      unsigned short* vtb = Vt + (size_t)b * 262144;
      #pragma unroll
      for (int mi = 0; mi < 4; ++mi)
        #pragma unroll
        for (int reg = 0; reg < 4; ++reg) {
          int c = r0 + mi * 16 + quad * 4 + reg;
          int kc = c >> 5, cq = (c >> 3) & 3, e8 = c & 7;
          int lp = cq * 16 + m;
          vtb[((kc * 8 + w * 2) * 64 + lp) * 8 + e8]       = f2bf_fast(acc[mi][0][reg] + bv0);
          vtb[((kc * 8 + w * 2 + 1) * 64 + lp) * 8 + e8]   = f2bf_fast(acc[mi][1][reg] + bv1);
        }
      pq  += __shfl_xor(pq, 1);  pq  += __shfl_xor(pq, 2);
      pk2 += __shfl_xor(pk2, 1); pk2 += __shfl_xor(pk2, 2);
      if ((t & 3) == 0) {
        sq[(size_t)b * kC + nl] = pq + u2[(size_t)l * 272 + 256];
        sk[(size_t)b * kC + nl] = pk2;
      }
    }
  } else {
    // layer begin/end: reads feats, writes seq rows N, N+1
    int rb = bid - 512;
    int b = rb >> 1, sel = rb & 1;
    float* msh = (float*)smem;
    const int* idx = (sel ? r.eidx : r.bidx) + b * kJ;
    const void* wv = sel ? r.bew : r.bbw;
    const void* bb = sel ? r.beb : r.bbb;
    size_t wbase = (size_t)l * kD * kD, bbase = (size_t)l * kD;
    if (t < 128) {
      int d = t;
      const float* fb2 = feats + (size_t)b * kC * kD;
      float acc = 0.f;
      for (int j = 0; j < kJ; ++j) acc += fb2[(size_t)idx[j] * kD + d];
      msh[d] = acc * (1.0f / kJ);
    }
    __syncthreads();
    if (t < 128) {
      int d = t;
      float o = rp(bb, bbase + d, bf);
      for (int k = 0; k < kD; ++k) o += msh[k] * rp(wv, wbase + (size_t)k * kD + d, bf);
      seq[(size_t)b * kC * kD + (size_t)(kN + sel) * kD + d] = o;
    }
  }
}

// ---------- K2: MFMA PV with fused softmax stats ----------
__global__ __launch_bounds__(256) void k_attn_pv_mfma(
    const unsigned* __restrict__ bits,
    const float* __restrict__ sq, const float* __restrict__ sk,
    const unsigned short* __restrict__ Vt,     // fragment layout per batch
    float* __restrict__ outw)
{
  int b = blockIdx.y;
  int i0 = blockIdx.x * 32;
  int t = threadIdx.x, lane = t & 63, w = t >> 6;

  __shared__ unsigned short pshare[2][1024];
  __shared__ float sklds[kC];
  __shared__ unsigned bitlds[2048];
  __shared__ float ssq[32], smx[32], szv[32];

  const float* skb = sk + (size_t)b * kC;
  #pragma unroll
  for (int q = 0; q < 8; ++q) sklds[q * 256 + t] = skb[q * 256 + t];
  const unsigned* bitrow = bits + ((size_t)b * kC + i0) * 64;
  #pragma unroll
  for (int q = 0; q < 8; ++q) bitlds[q * 256 + t] = bitrow[q * 256 + t];
  if (t < 32) ssq[t] = sq[(size_t)b * kC + i0 + t];
  __syncthreads();

  {
    int rr = t >> 3, seg = t & 7;
    int ig = i0 + rr;
    bool ok = (ig < kN);
    float sqi2 = ssq[rr];
    const unsigned* bw = bitlds + rr * 64 + seg * 8;
    const float* sks = sklds + seg * 256;
    float mx;
    if (ok) {
      float msk = -3e38f;
      #pragma unroll 1
      for (int w8 = 0; w8 < 8; ++w8) {
        unsigned bb = bw[w8];
        #pragma unroll
        for (int q4 = 0; q4 < 8; ++q4) {
          float4 skv = *(const float4*)(sks + w8 * 32 + q4 * 4);
          unsigned nib = bb >> (q4 * 4);
          msk = (nib & 1u) ? fmaxf(msk, skv.x) : msk;
          msk = (nib & 2u) ? fmaxf(msk, skv.y) : msk;
          msk = (nib & 4u) ? fmaxf(msk, skv.z) : msk;
          msk = (nib & 8u) ? fmaxf(msk, skv.w) : msk;
        }
      }
      #pragma unroll
      for (int d2 = 1; d2 < 8; d2 <<= 1) msk = fmaxf(msk, __shfl_xor(msk, d2));
      float s = sqi2 + msk;
      mx = fmaxf(0.f, fmaxf(s, 0.01f * s));
    } else {
      float s = sqi2 + sklds[ig & (kC - 1)];
      mx = fmaxf(0.f, fmaxf(s, 0.01f * s));
    }
    float emx = __expf(-mx);
    float zs = 0.f;
    if (ok) {
      #pragma unroll 1
      for (int w8 = 0; w8 < 8; ++w8) {
        unsigned bb = bw[w8];
        #pragma unroll
        for (int q4 = 0; q4 < 8; ++q4) {
          float4 skv = *(const float4*)(sks + w8 * 32 + q4 * 4);
          unsigned nib = bb >> (q4 * 4);
          float s1 = sqi2 + skv.x, l1 = fmaxf(s1, 0.01f * s1);
          float s2 = sqi2 + skv.y, l2 = fmaxf(s2, 0.01f * s2);
          float s3 = sqi2 + skv.z, l3 = fmaxf(s3, 0.01f * s3);
          float s4 = sqi2 + skv.w, l4 = fmaxf(s4, 0.01f * s4);
          zs += (nib & 1u) ? __expf(l1 - mx) : emx;
          zs += (nib & 2u) ? __expf(l2 - mx) : emx;
          zs += (nib & 4u) ? __expf(l3 - mx) : emx;
          zs += (nib & 8u) ? __expf(l4 - mx) : emx;
        }
      }
    } else {
      zs = 256.f * emx;
      if ((ig >> 8) == seg) {
        float s = sqi2 + sklds[ig & (kC - 1)];
        float lr = fmaxf(s, 0.01f * s);
        zs += __expf(lr - mx) - emx;
      }
    }
    #pragma unroll
    for (int d2 = 1; d2 < 8; d2 <<= 1) zs += __shfl_xor(zs, d2);
    if (seg == 0) { smx[rr] = mx; szv[rr] = 1.0f / zs; }
  }
  __syncthreads();

  int f = t >> 1, h = t & 1;
  int mt_b = f >> 6;
  int lb = f & 63;
  int irow_l = mt_b * 16 + (lb & 15);
  int quad_b = lb >> 4;
  int i_g = i0 + irow_l;
  float sqi = ssq[irow_l];
  float mri = smx[irow_l];
  int joff = quad_b * 8 + h * 4;
  bool irow_ok = (i_g < kN);
  const unsigned char* bitb = (const unsigned char*)bitlds + irow_l * 256;

  auto buildP = [&](int k0, int buf) {
    float4 skv = *(const float4*)(sklds + k0 + joff);
    unsigned byte;
    if (irow_ok) {
      byte = bitb[(k0 >> 3) + quad_b];
    } else {
      int d0 = i_g - (k0 + quad_b * 8);
      byte = ((unsigned)d0 < 8u) ? (1u << d0) : 0u;
    }
    unsigned nib = byte >> (h * 4);
    unsigned short us[4];
    float sv[4] = {skv.x, skv.y, skv.z, skv.w};
    #pragma unroll
    for (int dj = 0; dj < 4; ++dj) {
      float s = sqi + sv[dj];
      float lr = fmaxf(s, 0.01f * s);
      float val = ((nib >> dj) & 1u) ? lr : 0.f;
      us[dj] = f2bf_fast(__expf(val - mri));
    }
    uint2 pk;
    pk.x = us[0] | ((unsigned)us[1] << 16);
    pk.y = us[2] | ((unsigned)us[3] << 16);
    *(uint2*)(&pshare[buf][f * 8 + h * 4]) = pk;
  };

  f32x4 acc00 = {0.f, 0.f, 0.f, 0.f}, acc01 = acc00, acc10 = acc00, acc11 = acc00;
  int m = lane & 15, quad = lane >> 4;
  int nbase = w * 32;
  const unsigned short* vtb = Vt + (size_t)b * 262144;
  const unsigned short* p0 = vtb + (size_t)(w * 2) * 512 + lane * 8;
  const unsigned short* p1 = p0 + 512;

  buildP(0, 0);
  bfrag8 b0n = *(const bfrag8*)p0;
  bfrag8 b1n = *(const bfrag8*)p1;
  __syncthreads();

  for (int k0 = 0; k0 < kC; k0 += 32) {
    int cur = (k0 >> 5) & 1;
    bfrag8 bf0 = b0n, bf1 = b1n;
    if (k0 + 32 < kC) {
      size_t off = (size_t)((k0 >> 5) + 1) * 4096;
      b0n = *(const bfrag8*)(p0 + off);
      b1n = *(const bfrag8*)(p1 + off);
    }
    bfrag8 a0 = *(const bfrag8*)(&pshare[cur][(0 * 64 + lane) * 8]);
    bfrag8 a1 = *(const bfrag8*)(&pshare[cur][(1 * 64 + lane) * 8]);
    acc00 = mfma16(a0, bf0, acc00);
    acc01 = mfma16(a0, bf1, acc01);
    acc10 = mfma16(a1, bf0, acc10);
    acc11 = mfma16(a1, bf1, acc11);
    if (k0 + 32 < kC) buildP(k0 + 32, cur ^ 1);
    __syncthreads();
  }

  #pragma unroll
  for (int reg = 0; reg < 4; ++reg) {
    int il_a = quad * 4 + reg;
    int i_a = i0 + il_a;
    int i_b = i_a + 16;
    float za = szv[il_a];
    float zb = szv[il_a + 16];
    float* oa = outw + ((size_t)b * kC + i_a) * kD + nbase + m;
    float* ob = outw + ((size_t)b * kC + i_b) * kD + nbase + m;
    oa[0]  = acc00[reg] * za;
    oa[16] = acc01[reg] * za;
    ob[0]  = acc10[reg] * zb;
    ob[16] = acc11[reg] * zb;
  }
}

// ---------- K3: mix GEMM (K=256, 64-row tiles); mode1 writes outputs ----------
__global__ __launch_bounds__(256) void k_mix64(Raw r, int l,
    const float* __restrict__ seqb, const float* __restrict__ attnw,
    const unsigned short* __restrict__ wt, const float* __restrict__ bmix,
    float* __restrict__ featsOut, void* __restrict__ outx, float* __restrict__ part,
    int mode)
{
  __shared__ __align__(16) char smem[20480];
  unsigned short (*Ah)[64 * 40] = (unsigned short(*)[64 * 40])smem;
  unsigned short (*Al)[64 * 40] = (unsigned short(*)[64 * 40])(smem + 10240);
  constexpr int K = 256;
  int bid = blockIdx.x, t = threadIdx.x;
  int lane = t & 63, w = t >> 6, m = lane & 15, quad = lane >> 4;
  bool bf = sniff(r);
  int gr0 = bid * 64;
  int b = gr0 >> 11;
  int arow = t >> 2, kq = (t & 3) * 8;
  const float* s0 = seqb  + (size_t)(gr0 + arow) * kD;
  const float* s1 = attnw + (size_t)(gr0 + arow) * kD;
  const unsigned short* wth = wt + (size_t)l * WT_LS + WT_MIXH;
  const unsigned short* wtl = wt + (size_t)l * WT_LS + WT_MIXL;
  const unsigned short* pbh = wth + (size_t)(w * 2) * 512 + lane * 8;
  const unsigned short* pbl = wtl + (size_t)(w * 2) * 512 + lane * 8;

  auto build = [&](int kb, int buf) {
    int kg = kb + kq;
    const float* sp = (kg < kD) ? (s0 + kg) : (s1 + kg - kD);
    float4 xa = *(const float4*)sp;
    float4 xb = *(const float4*)(sp + 4);
    unsigned short h[8], lo[8];
    split2(xa.x, h[0], lo[0]); split2(xa.y, h[1], lo[1]);
    split2(xa.z, h[2], lo[2]); split2(xa.w, h[3], lo[3]);
    split2(xb.x, h[4], lo[4]); split2(xb.y, h[5], lo[5]);
    split2(xb.z, h[6], lo[6]); split2(xb.w, h[7], lo[7]);
    uint4 ph, pl;
    ph.x = h[0] | ((unsigned)h[1] << 16);  ph.y = h[2] | ((unsigned)h[3] << 16);
    ph.z = h[4] | ((unsigned)h[5] << 16);  ph.w = h[6] | ((unsigned)h[7] << 16);
    pl.x = lo[0] | ((unsigned)lo[1] << 16); pl.y = lo[2] | ((unsigned)lo[3] << 16);
    pl.z = lo[4] | ((unsigned)lo[5] << 16); pl.w = lo[6] | ((unsigned)lo[7] << 16);
    *(uint4*)&Ah[buf][arow * 40 + kq] = ph;
    *(uint4*)&Al[buf][arow * 40 + kq] = pl;
  };

  f32x4 acc[4][2];
  #pragma unroll
  for (int mi = 0; mi < 4; ++mi) { acc[mi][0] = {0.f,0.f,0.f,0.f}; acc[mi][1] = {0.f,0.f,0.f,0.f}; }

  build(0, 0);
  __syncthreads();
  for (int kb = 0; kb < K; kb += 32) {
    int cur = (kb >> 5) & 1;
    int kc = kb >> 5;
    bfrag8 bh0 = *(const bfrag8*)(pbh + (size_t)kc * 4096);
    bfrag8 bh1 = *(const bfrag8*)(pbh + (size_t)kc * 4096 + 512);
    bfrag8 bl0 = {}, bl1 = {};
    if (!bf) {
      bl0 = *(const bfrag8*)(pbl + (size_t)kc * 4096);
      bl1 = *(const bfrag8*)(pbl + (size_t)kc * 4096 + 512);
    }
    if (kb + 32 < K) build(kb + 32, cur ^ 1);
    #pragma unroll
    for (int mi = 0; mi < 4; ++mi) {
      bfrag8 ah = *(const bfrag8*)&Ah[cur][(mi * 16 + m) * 40 + quad * 8];
      bfrag8 al = *(const bfrag8*)&Al[cur][(mi * 16 + m) * 40 + quad * 8];
      acc[mi][0] = mfma16(ah, bh0, acc[mi][0]);
      acc[mi][0] = mfma16(al, bh0, acc[mi][0]);
      acc[mi][1] = mfma16(ah, bh1, acc[mi][1]);
      acc[mi][1] = mfma16(al, bh1, acc[mi][1]);
      if (!bf) {
        acc[mi][0] = mfma16(ah, bl0, acc[mi][0]);
        acc[mi][1] = mfma16(ah, bl1, acc[mi][1]);
      }
    }
    __syncthreads();
  }

  int n0 = w * 32 + m;
  float bv0 = bmix[(size_t)l * kD + n0];
  float bv1 = bmix[(size_t)l * kD + n0 + 16];
  if (mode == 0) {
    #pragma unroll
    for (int mi = 0; mi < 4; ++mi)
      #pragma unroll
      for (int reg = 0; reg < 4; ++reg) {
        size_t row = (size_t)gr0 + mi * 16 + quad * 4 + reg;
        featsOut[row * kD + n0]      = acc[mi][0][reg] + bv0;
        featsOut[row * kD + n0 + 16] = acc[mi][1][reg] + bv1;
      }
  } else {
    float sum0 = 0.f, sum1 = 0.f;
    #pragma unroll
    for (int mi = 0; mi < 4; ++mi)
      #pragma unroll
      for (int reg = 0; reg < 4; ++reg) {
        size_t row = (size_t)gr0 + mi * 16 + quad * 4 + reg;
        float v0 = acc[mi][0][reg] + bv0;
        float v1 = acc[mi][1][reg] + bv1;
        if (bf) {
          unsigned short* o = (unsigned short*)outx + 1024;
          o[row * kD + n0]      = f2bf(v0);
          o[row * kD + n0 + 16] = f2bf(v1);
        } else {
          float* o = (float*)outx + 1024;
          o[row * kD + n0]      = v0;
          o[row * kD + n0 + 16] = v1;
        }
        sum0 += v0; sum1 += v1;
      }
    sum0 += __shfl_xor(sum0, 16); sum0 += __shfl_xor(sum0, 32);
    sum1 += __shfl_xor(sum1, 16); sum1 += __shfl_xor(sum1, 32);
    if (quad == 0) {
      atomicAdd(&part[(size_t)b * kD + n0],      sum0);
      atomicAdd(&part[(size_t)b * kD + n0 + 16], sum1);
    }
  }
}

// ---------- K4: final mean ----------
__global__ __launch_bounds__(128) void k_mean(Raw r, const float* __restrict__ part,
                                              void* __restrict__ out) {
  bool bf = sniff(r);
  int b = blockIdx.x, d = threadIdx.x;
  float v = part[(size_t)b * kD + d] * (1.0f / kC);
  if (bf) ((unsigned short*)out)[b * kD + d] = f2bf(v);
  else    ((float*)out)[b * kD + d] = v;
}

extern "C" void kernel_launch(void* const* d_in, const int* in_sizes, int n_in,
                              void* d_out, int out_size, void* d_ws, size_t ws_size,
                              hipStream_t stream) {
  Raw r;
  r.ops = d_in[0];  r.mask = d_in[1];
  r.rel = (const int*)d_in[2]; r.bidx = (const int*)d_in[3]; r.eidx = (const int*)d_in[4];
  r.ibw = d_in[5];  r.ibb = d_in[6];  r.iew = d_in[7];  r.ieb = d_in[8];
  r.bbw = d_in[9];  r.bbb = d_in[10]; r.bew = d_in[11]; r.beb = d_in[12];
  r.sw  = d_in[13]; r.sb  = d_in[14]; r.aw  = d_in[15]; r.ab  = d_in[16];
  r.scw = d_in[17]; r.scb = d_in[18]; r.aow = d_in[19]; r.aob = d_in[20];
  r.mw  = d_in[21]; r.mb  = d_in[22];

  float* ws    = (float*)d_ws;
  float* feats = ws + OF_FEATS;
  float* seq   = ws + OF_SEQ;
  float* attnw = ws + OF_ATTN;
  float* sq    = ws + OF_SQ;
  float* sk    = ws + OF_SK;
  float* u2    = ws + OF_U;
  float* part  = ws + OF_PART;
  float* bmix  = ws + OF_BMIX;
  unsigned short* wt = (unsigned short*)(ws + OF_WT);
  unsigned short* Vt = (unsigned short*)(ws + OF_V);
  unsigned*     bits = (unsigned*)(ws + OF_V + 1048576);

  k_prep<<<RP_TOT, 256, 0, stream>>>(r, feats, bits, wt, bmix, u2, part);
  k_mask<<<16353, 256, 0, stream>>>(r, bits);

  for (int l = 0; l < kL; ++l) {
    k_stage1<<<528, 256, 0, stream>>>(r, l, feats, wt, u2, seq, Vt, sq, sk);
    k_attn_pv_mfma<<<dim3(64, kB), 256, 0, stream>>>(bits, sq, sk, Vt, attnw);
    k_mix64<<<256, 256, 0, stream>>>(r, l, seq, attnw, wt, bmix, feats, d_out, part,
                                     (l == kL - 1) ? 1 : 0);
  }

  k_mean<<<kB, 128, 0, stream>>>(r, part, d_out);
}

// Round 10
// 470.154 us; speedup vs baseline: 1.1959x; 1.1959x over previous
//
#include <hip/hip_runtime.h>

// Problem constants
constexpr int kB = 8;
constexpr int kN = 2046;
constexpr int kC = 2048;   // kN + 2
constexpr int kD = 128;
constexpr int kJ = 128;
constexpr int kL = 2;

typedef short bfrag8 __attribute__((ext_vector_type(8)));
typedef float f32x4 __attribute__((ext_vector_type(4)));

// ---------- bf16 helpers ----------
__device__ __forceinline__ float bf2f(unsigned short h) {
  union { unsigned u; float f; } x; x.u = ((unsigned)h) << 16; return x.f;
}
__device__ __forceinline__ float uasf(unsigned u) {
  union { unsigned u; float f; } x; x.u = u; return x.f;
}
__device__ __forceinline__ unsigned short f2bf(float f) {
  union { float f; unsigned u; } x; x.f = f;
  unsigned u = x.u;
  if ((u & 0x7fffffffu) > 0x7f800000u) return (unsigned short)((u >> 16) | 0x40);
  return (unsigned short)((u + 0x7fffu + ((u >> 16) & 1u)) >> 16);
}
__device__ __forceinline__ unsigned short f2bf_fast(float f) {  // finite inputs
  union { float f; unsigned u; } x; x.f = f;
  return (unsigned short)((x.u + 0x7fffu + ((x.u >> 16) & 1u)) >> 16);
}
__device__ __forceinline__ void split2(float x, unsigned short& h, unsigned short& l) {
  unsigned short hh = f2bf_fast(x);
  h = hh;
  l = f2bf_fast(x - bf2f(hh));
}
// pack f32 -> (hi bf16 <<16) | lo bf16
__device__ __forceinline__ unsigned pack2(float x) {
  unsigned short h, l;
  split2(x, h, l);
  return ((unsigned)h << 16) | (unsigned)l;
}
// unpack packed -> f32 (hi + lo)
__device__ __forceinline__ float unpack2(unsigned v) {
  return uasf(v & 0xFFFF0000u) + uasf(v << 16);
}

// ---------- raw input pointers ----------
struct Raw {
  const void *ops, *mask;
  const int *rel, *bidx, *eidx;
  const void *ibw, *ibb, *iew, *ieb;       // init begin/end proj
  const void *bbw, *bbb, *bew, *beb;       // per-layer begin/end proj
  const void *sw, *sb;                     // seq_mix
  const void *aw, *ab;                     // attn_w
  const void *scw, *scb;                   // score
  const void *aow, *aob;                   // attn_out
  const void *mw, *mb;                     // mix
};

__device__ __forceinline__ float rp(const void* p, size_t i, bool bf) {
  return bf ? bf2f(((const unsigned short*)p)[i]) : ((const float*)p)[i];
}

// per-wave dtype sniff over first 1024 words of operation_features
__device__ __forceinline__ bool sniff(const Raw& r) {
  const unsigned* x = (const unsigned*)r.ops;
  int lane = (int)(threadIdx.x & 63);
  int hits = 0;
  #pragma unroll
  for (int q = 0; q < 16; ++q) {
    unsigned w = x[q * 64 + lane];
    unsigned e0 = (w >> 7) & 0xFFu;
    hits += (e0 == 0u || (e0 >= 96u && e0 <= 134u)) ? 1 : 0;
  }
  #pragma unroll
  for (int o = 1; o < 64; o <<= 1) hits += __shfl_xor(hits, o);
  return hits >= 512;
}

// ---------- workspace layout (float offsets) ----------
// feats/seq/attn stored PACKED: one u32 = (hi bf16 << 16) | lo bf16 per element
constexpr size_t OF_FEATS = 0;                       // 1M u32 used
constexpr size_t OF_SEQ   = 2097152;
constexpr size_t OF_ATTN  = 4194304;
constexpr size_t OF_V     = 6291456;                 // VtF (1M floats) + bits (1M floats)
constexpr size_t OF_SQ    = 8388608;
constexpr size_t OF_SK    = 8404992;
constexpr size_t OF_U     = 8421376;
constexpr size_t OF_PART  = 8422400;
constexpr size_t OF_BMIX  = 8423424;
constexpr size_t OF_WT    = 8423680;                 // ushort arena

// Wt arena (ushort offsets), per-layer stride. Fragment layout:
// frag(kc, nt, lane, e): element (n = nt*16 + (lane&15), k = kc*32 + (lane>>4)*8 + e)
constexpr int WT_SEQH = 0;        // K=384
constexpr int WT_SEQL = 49152;
constexpr int WT_VH   = 98304;    // K=128
constexpr int WT_VL   = 114688;
constexpr int WT_MIXH = 131072;   // K=256
constexpr int WT_MIXL = 163840;
constexpr int WT_LS   = 196608;

// prep role boundaries (mask + zero-bits removed)
constexpr int RP_CAST = 4092;
constexpr int RP_WT   = RP_CAST + 640;   // 4732
constexpr int RP_WF   = RP_WT + 258;     // 4990
constexpr int RP_UV   = RP_WF + 2;       // 4992
constexpr int RP_BE   = RP_UV + 16;      // 5008
constexpr int RP_TOT  = RP_BE + 1;       // 5009 (zero part)

// ---------- MFMA helper ----------
__device__ __forceinline__ f32x4 mfma16(bfrag8 a, bfrag8 b, f32x4 c) {
  return __builtin_amdgcn_mfma_f32_16x16x32_bf16(a, b, c, 0, 0, 0);
}

// ---------- K0a: mask -> bits. One block per row; 1-2 uint4 loads per thread, LDS assemble. ----------
__global__ __launch_bounds__(256) void k_mask(Raw r, unsigned* __restrict__ bits32) {
  __shared__ unsigned char sb[256];
  bool bf = sniff(r);
  int row = blockIdx.x;              // 0..B*kN-1
  int b = row / kN, i = row - b * kN;
  int t = threadIdx.x;
  unsigned bb = 0;
  if (bf) {
    const char* base = (const char*)r.mask + (size_t)row * (kN * 2);
    int off = (t < 255) ? (t * 16) : 4076;          // t=255 covers elems 2038..2045
    uint4 v = *(const uint4*)(base + off);           // 4B-aligned; dword alignment is legal
    unsigned u[4] = {v.x, v.y, v.z, v.w};
    #pragma unroll
    for (int k = 0; k < 8; ++k) {
      unsigned h = (u[k >> 1] >> ((k & 1) * 16)) & 0xFFFFu;
      bb |= (h != 0u) ? (1u << k) : 0u;
    }
  } else {
    const char* base = (const char*)r.mask + (size_t)row * (kN * 4);
    int off = (t < 255) ? (t * 32) : 8152;          // t=255 covers elems 2038..2045
    uint4 a = *(const uint4*)(base + off);
    uint4 c = *(const uint4*)(base + off + 16);
    unsigned u[8] = {a.x, a.y, a.z, a.w, c.x, c.y, c.z, c.w};
    #pragma unroll
    for (int k = 0; k < 8; ++k) bb |= (u[k] != 0u) ? (1u << k) : 0u;
  }
  // t<255: byte covers bits [8t, 8t+8). t==255: bits [2040,2048) = elems 2..7 of its load, top 2 zero.
  sb[t] = (t < 255) ? (unsigned char)bb : (unsigned char)((bb >> 2) & 0x3Fu);
  __syncthreads();
  if (t < 64) {
    unsigned w = *(const unsigned*)(sb + 4 * t);
    bits32[((size_t)b * kC + i) * 64 + t] = w;
  }
}

// ---------- K0b: prep (cast, weights, fuse, uvec, init begin/end, zero part) ----------
__global__ __launch_bounds__(256) void k_prep(Raw r, unsigned* __restrict__ feats,
                                              unsigned short* __restrict__ wt,
                                              float* __restrict__ bmix,
                                              float* __restrict__ u2,
                                              float* __restrict__ part) {
  __shared__ __align__(16) char smem[4096];
  int bid = blockIdx.x, t = threadIdx.x;
  bool bf = sniff(r);

  if (bid < RP_CAST) {
    // cast ops -> packed feats rows 0..N-1 (2 elements per thread)
    int idx = bid * 256 + t;
    int elem = idx * 2;
    int b = elem / (kN * kD);
    int rr = elem - b * (kN * kD);
    uint2 o;
    if (bf) {
      unsigned u = ((const unsigned*)r.ops)[idx];
      o.x = u << 16;            // hi = input bf16, lo = 0
      o.y = u & 0xFFFF0000u;
    } else {
      float2 f = ((const float2*)r.ops)[idx];
      o.x = pack2(f.x);
      o.y = pack2(f.y);
    }
    *(uint2*)(feats + (size_t)b * kC * kD + rr) = o;
  } else if (bid < RP_WT) {
    // transpose+split weights into fragment layout
    int idx = (bid - RP_CAST) * 256 + t;   // < 163840
    int l = idx / 81920;
    int rr = idx - l * 81920;
    const void* src; size_t si; int dH, dL, k, n;
    if (rr < 49152) {
      k = rr >> 7; n = rr & 127;
      src = r.sw; si = (size_t)l * 49152 + (size_t)k * 128 + n;
      dH = l * WT_LS + WT_SEQH; dL = l * WT_LS + WT_SEQL;
    } else if (rr < 65536) {
      int e = rr - 49152; k = e >> 7; n = e & 127;
      src = r.aw; si = (size_t)l * 49152 + (size_t)k * 384 + 256 + n;
      dH = l * WT_LS + WT_VH; dL = l * WT_LS + WT_VL;
    } else {
      int e = rr - 65536; k = e >> 7; n = e & 127;
      src = r.mw; si = (size_t)l * 32768 + (size_t)k * 128 + n;
      dH = l * WT_LS + WT_MIXH; dL = l * WT_LS + WT_MIXL;
    }
    float v = rp(src, si, bf);
    unsigned short h, lo;
    split2(v, h, lo);
    int kc = k >> 5, q = (k >> 3) & 3, e8 = k & 7;
    int fa = ((kc * 8 + (n >> 4)) * 64 + (q * 16 + (n & 15))) * 8 + e8;
    wt[dH + fa] = h;
    wt[dL + fa] = lo;
  } else if (bid < RP_WF) {
    // fuse ao_w @ mix_bot -> mix fragments k in [128,256)
    int rb = bid - RP_WT;
    int l = rb / 129, d1 = rb - l * 129;
    if (t < 128) {
      int d = t;
      size_t mixbot = (size_t)l * 32768 + 16384;
      if (d1 < 128) {
        float acc = 0.f;
        for (int d2 = 0; d2 < kD; ++d2)
          acc += rp(r.aow, (size_t)l * 16384 + (size_t)d1 * 128 + d2, bf)
               * rp(r.mw, mixbot + (size_t)d2 * 128 + d, bf);
        unsigned short h, lo;
        split2(acc, h, lo);
        int k = 128 + d1;
        int kc = k >> 5, q = (k >> 3) & 3, e8 = k & 7;
        int fa = ((kc * 8 + (d >> 4)) * 64 + (q * 16 + (d & 15))) * 8 + e8;
        wt[l * WT_LS + WT_MIXH + fa] = h;
        wt[l * WT_LS + WT_MIXL + fa] = lo;
      } else {
        float acc = rp(r.mb, (size_t)l * 128 + d, bf);
        for (int d2 = 0; d2 < kD; ++d2)
          acc += rp(r.aob, (size_t)l * 128 + d2, bf)
               * rp(r.mw, mixbot + (size_t)d2 * 128 + d, bf);
        bmix[(size_t)l * kD + d] = acc;
      }
    }
  } else if (bid < RP_UV) {
    // u-vectors
    int l = bid - RP_WF;
    float* swm = (float*)smem;
    float* red = (float*)smem + 256;
    if (t < 128) {
      swm[t]       = rp(r.scw, (size_t)l * 256 + t, bf);
      swm[128 + t] = rp(r.scw, (size_t)l * 256 + 128 + t, bf);
    }
    __syncthreads();
    if (t < 128) {
      int k = t;
      size_t base = (size_t)l * 49152 + (size_t)k * 384;
      float uq = 0.f, uk = 0.f;
      for (int d2 = 0; d2 < kD; ++d2) {
        uq += rp(r.aw, base + d2, bf) * swm[d2];
        uk += rp(r.aw, base + 128 + d2, bf) * swm[128 + d2];
      }
      float* u = u2 + (size_t)l * 272;
      u[k] = uq; u[128 + k] = uk;
      red[k] = rp(r.ab, (size_t)l * 384 + k, bf) * swm[k]
             + rp(r.ab, (size_t)l * 384 + 128 + k, bf) * swm[128 + k];
    }
    __syncthreads();
    if (t == 0) {
      float s = rp(r.scb, l, bf);
      for (int i = 0; i < 128; ++i) s += red[i];
      u2[(size_t)l * 272 + 256] = s;
    }
  } else if (bid < RP_BE) {
    // init begin/end -> packed feats rows N, N+1
    int rb = bid - RP_UV;
    int b = rb >> 1, sel = rb & 1;
    float* msh = (float*)smem;
    const int* idx = (sel ? r.eidx : r.bidx) + b * kJ;
    const void* wv = sel ? r.iew : r.ibw;
    const void* bb = sel ? r.ieb : r.ibb;
    if (t < 128) {
      int d = t;
      float acc = 0.f;
      for (int j = 0; j < kJ; ++j)
        acc += rp(r.ops, ((size_t)b * kN + idx[j]) * kD + d, bf);
      msh[d] = acc * (1.0f / kJ);
    }
    __syncthreads();
    if (t < 128) {
      int d = t;
      float o = rp(bb, d, bf);
      for (int k = 0; k < kD; ++k) o += msh[k] * rp(wv, (size_t)k * kD + d, bf);
      feats[(size_t)b * kC * kD + (size_t)(kN + sel) * kD + d] = pack2(o);
    }
  } else {
    #pragma unroll
    for (int q = 0; q < 4; ++q) part[q * 256 + t] = 0.f;
  }
}

// ---------- K1: stage1 — seq GEMM + vproj GEMM + layer begin/end (packed IO) ----------
__global__ __launch_bounds__(256) void k_stage1(Raw r, int l,
    const unsigned* __restrict__ feats, const unsigned short* __restrict__ wt,
    const float* __restrict__ u2, unsigned* __restrict__ seq,
    unsigned short* __restrict__ Vt, float* __restrict__ sq, float* __restrict__ sk)
{
  __shared__ __align__(16) char smem[21504];
  unsigned short (*Ah)[64 * 40] = (unsigned short(*)[64 * 40])smem;
  unsigned short (*Al)[64 * 40] = (unsigned short(*)[64 * 40])(smem + 10240);
  float* su = (float*)(smem + 20480);
  int bid = blockIdx.x, t = threadIdx.x;
  int lane = t & 63, w = t >> 6, m = lane & 15, quad = lane >> 4;
  bool bf = sniff(r);
  const unsigned short* wl = wt + (size_t)l * WT_LS;

  if (bid < 512) {
    bool isv = bid >= 256;
    int rb = isv ? bid - 256 : bid;
    int gr0 = rb * 64;
    int b = gr0 >> 11, r0 = gr0 & 2047;
    int arow = t >> 2, kq = (t & 3) * 8;
    int nl = r0 + arow;
    const unsigned* fb = feats + (size_t)b * kC * kD;
    const unsigned *s0, *s1, *s2;
    if (!isv) {
      int nr = (nl <= kN - 1) ? nl : (kN - 1);
      const int* rel = r.rel + ((size_t)b * kN + nr) * 2;
      int rpd = rel[0], rsc = rel[1];
      int p = (rpd < 0) ? kN : rpd;
      int s = (rsc < 0) ? (kN + 1) : rsc;
      s0 = fb + (size_t)nl * kD;
      s1 = fb + (size_t)p * kD;
      s2 = fb + (size_t)s * kD;
    } else {
      s0 = fb + (size_t)nl * kD; s1 = s0; s2 = s0;
      su[t] = u2[(size_t)l * 272 + t];
    }
    const int K = isv ? 128 : 384;
    const unsigned short* wth = isv ? (wl + WT_VH) : (wl + WT_SEQH);
    const unsigned short* wtl = isv ? (wl + WT_VL) : (wl + WT_SEQL);
    const unsigned short* pbh = wth + (size_t)(w * 2) * 512 + lane * 8;
    const unsigned short* pbl = wtl + (size_t)(w * 2) * 512 + lane * 8;
    float pq = 0.f, pk2 = 0.f;

    auto build = [&](int kb, int buf) {
      int kg = kb + kq;
      const unsigned* sp;
      if (!isv) sp = (kg < 128) ? (s0 + kg) : (kg < 256) ? (s1 + kg - 128) : (s2 + kg - 256);
      else      sp = s0 + kg;
      uint4 v0 = *(const uint4*)sp;
      uint4 v1 = *(const uint4*)(sp + 4);
      if (isv) {
        unsigned uu[8] = {v0.x, v0.y, v0.z, v0.w, v1.x, v1.y, v1.z, v1.w};
        #pragma unroll
        for (int j = 0; j < 8; ++j) {
          float x = unpack2(uu[j]);
          pq  += x * su[kg + j];
          pk2 += x * su[128 + kg + j];
        }
      }
      uint4 ph, pl;
      ph.x = (v0.x >> 16) | (v0.y & 0xFFFF0000u);
      ph.y = (v0.z >> 16) | (v0.w & 0xFFFF0000u);
      ph.z = (v1.x >> 16) | (v1.y & 0xFFFF0000u);
      ph.w = (v1.z >> 16) | (v1.w & 0xFFFF0000u);
      pl.x = (v0.x & 0xFFFFu) | (v0.y << 16);
      pl.y = (v0.z & 0xFFFFu) | (v0.w << 16);
      pl.z = (v1.x & 0xFFFFu) | (v1.y << 16);
      pl.w = (v1.z & 0xFFFFu) | (v1.w << 16);
      *(uint4*)&Ah[buf][arow * 40 + kq] = ph;
      *(uint4*)&Al[buf][arow * 40 + kq] = pl;
    };

    f32x4 acc[4][2];
    #pragma unroll
    for (int mi = 0; mi < 4; ++mi) { acc[mi][0] = {0.f,0.f,0.f,0.f}; acc[mi][1] = {0.f,0.f,0.f,0.f}; }

    __syncthreads();   // su visible
    build(0, 0);
    __syncthreads();
    for (int kb = 0; kb < K; kb += 32) {
      int cur = (kb >> 5) & 1;
      int kc = kb >> 5;
      bfrag8 bh0 = *(const bfrag8*)(pbh + (size_t)kc * 4096);
      bfrag8 bh1 = *(const bfrag8*)(pbh + (size_t)kc * 4096 + 512);
      bfrag8 bl0 = {}, bl1 = {};
      if (!bf) {
        bl0 = *(const bfrag8*)(pbl + (size_t)kc * 4096);
        bl1 = *(const bfrag8*)(pbl + (size_t)kc * 4096 + 512);
      }
      if (kb + 32 < K) build(kb + 32, cur ^ 1);
      #pragma unroll
      for (int mi = 0; mi < 4; ++mi) {
        bfrag8 ah = *(const bfrag8*)&Ah[cur][(mi * 16 + m) * 40 + quad * 8];
        bfrag8 al = *(const bfrag8*)&Al[cur][(mi * 16 + m) * 40 + quad * 8];
        acc[mi][0] = mfma16(ah, bh0, acc[mi][0]);
        acc[mi][0] = mfma16(al, bh0, acc[mi][0]);
        acc[mi][1] = mfma16(ah, bh1, acc[mi][1]);
        acc[mi][1] = mfma16(al, bh1, acc[mi][1]);
        if (!bf) {
          acc[mi][0] = mfma16(ah, bl0, acc[mi][0]);
          acc[mi][1] = mfma16(ah, bl1, acc[mi][1]);
        }
      }
      __syncthreads();
    }

    int n0 = w * 32 + m;
    if (!isv) {
      float bv0 = rp(r.sb, (size_t)l * 128 + n0, bf);
      float bv1 = rp(r.sb, (size_t)l * 128 + n0 + 16, bf);
      #pragma unroll
      for (int mi = 0; mi < 4; ++mi)
        #pragma unroll
        for (int reg = 0; reg < 4; ++reg) {
          int ra = r0 + mi * 16 + quad * 4 + reg;
          if (ra < kN) {
            seq[((size_t)b * kC + ra) * kD + n0]      = pack2(acc[mi][0][reg] + bv0);
            seq[((size_t)b * kC + ra) * kD + n0 + 16] = pack2(acc[mi][1][reg] + bv1);
          }
        }
    } else {
      float bv0 = rp(r.ab, (size_t)l * 384 + 256 + n0, bf);
      float bv1 = rp(r.ab, (size_t)l * 384 + 256 + n0 + 16, bf);
      unsigned short* vtb = Vt + (size_t)b * 262144;
      #pragma unroll
      for (int mi = 0; mi < 4; ++mi)
        #pragma unroll
        for (int reg = 0; reg < 4; ++reg) {
          int c = r0 + mi * 16 + quad * 4 + reg;
          int kc = c >> 5, cq = (c >> 3) & 3, e8 = c & 7;
          int lp = cq * 16 + m;
          vtb[((kc * 8 + w * 2) * 64 + lp) * 8 + e8]       = f2bf_fast(acc[mi][0][reg] + bv0);
          vtb[((kc * 8 + w * 2 + 1) * 64 + lp) * 8 + e8]   = f2bf_fast(acc[mi][1][reg] + bv1);
        }
      pq  += __shfl_xor(pq, 1);  pq  += __shfl_xor(pq, 2);
      pk2 += __shfl_xor(pk2, 1); pk2 += __shfl_xor(pk2, 2);
      if ((t & 3) == 0) {
        sq[(size_t)b * kC + nl] = pq + u2[(size_t)l * 272 + 256];
        sk[(size_t)b * kC + nl] = pk2;
      }
    }
  } else {
    // layer begin/end: reads packed feats, writes packed seq rows N, N+1
    int rb = bid - 512;
    int b = rb >> 1, sel = rb & 1;
    float* msh = (float*)smem;
    const int* idx = (sel ? r.eidx : r.bidx) + b * kJ;
    const void* wv = sel ? r.bew : r.bbw;
    const void* bb = sel ? r.beb : r.bbb;
    size_t wbase = (size_t)l * kD * kD, bbase = (size_t)l * kD;
    if (t < 128) {
      int d = t;
      const unsigned* fb2 = feats + (size_t)b * kC * kD;
      float acc = 0.f;
      for (int j = 0; j < kJ; ++j) acc += unpack2(fb2[(size_t)idx[j] * kD + d]);
      msh[d] = acc * (1.0f / kJ);
    }
    __syncthreads();
    if (t < 128) {
      int d = t;
      float o = rp(bb, bbase + d, bf);
      for (int k = 0; k < kD; ++k) o += msh[k] * rp(wv, wbase + (size_t)k * kD + d, bf);
      seq[(size_t)b * kC * kD + (size_t)(kN + sel) * kD + d] = pack2(o);
    }
  }
}

// ---------- K2: MFMA PV with fused softmax stats (packed output) ----------
__global__ __launch_bounds__(256) void k_attn_pv_mfma(
    const unsigned* __restrict__ bits,
    const float* __restrict__ sq, const float* __restrict__ sk,
    const unsigned short* __restrict__ Vt,     // fragment layout per batch
    unsigned* __restrict__ outw)               // packed
{
  int b = blockIdx.y;
  int i0 = blockIdx.x * 32;
  int t = threadIdx.x, lane = t & 63, w = t >> 6;

  __shared__ unsigned short pshare[2][1024];
  __shared__ float sklds[kC];
  __shared__ unsigned bitlds[2048];
  __shared__ float ssq[32], smx[32], szv[32];

  const float* skb = sk + (size_t)b * kC;
  #pragma unroll
  for (int q = 0; q < 8; ++q) sklds[q * 256 + t] = skb[q * 256 + t];
  const unsigned* bitrow = bits + ((size_t)b * kC + i0) * 64;
  #pragma unroll
  for (int q = 0; q < 8; ++q) bitlds[q * 256 + t] = bitrow[q * 256 + t];
  if (t < 32) ssq[t] = sq[(size_t)b * kC + i0 + t];
  __syncthreads();

  {
    int rr = t >> 3, seg = t & 7;
    int ig = i0 + rr;
    bool ok = (ig < kN);
    float sqi2 = ssq[rr];
    const unsigned* bw = bitlds + rr * 64 + seg * 8;
    const float* sks = sklds + seg * 256;
    float mx;
    if (ok) {
      float msk = -3e38f;
      #pragma unroll 1
      for (int w8 = 0; w8 < 8; ++w8) {
        unsigned bb = bw[w8];
        #pragma unroll
        for (int q4 = 0; q4 < 8; ++q4) {
          float4 skv = *(const float4*)(sks + w8 * 32 + q4 * 4);
          unsigned nib = bb >> (q4 * 4);
          msk = (nib & 1u) ? fmaxf(msk, skv.x) : msk;
          msk = (nib & 2u) ? fmaxf(msk, skv.y) : msk;
          msk = (nib & 4u) ? fmaxf(msk, skv.z) : msk;
          msk = (nib & 8u) ? fmaxf(msk, skv.w) : msk;
        }
      }
      #pragma unroll
      for (int d2 = 1; d2 < 8; d2 <<= 1) msk = fmaxf(msk, __shfl_xor(msk, d2));
      float s = sqi2 + msk;
      mx = fmaxf(0.f, fmaxf(s, 0.01f * s));
    } else {
      float s = sqi2 + sklds[ig & (kC - 1)];
      mx = fmaxf(0.f, fmaxf(s, 0.01f * s));
    }
    float emx = __expf(-mx);
    float zs = 0.f;
    if (ok) {
      #pragma unroll 1
      for (int w8 = 0; w8 < 8; ++w8) {
        unsigned bb = bw[w8];
        #pragma unroll
        for (int q4 = 0; q4 < 8; ++q4) {
          float4 skv = *(const float4*)(sks + w8 * 32 + q4 * 4);
          unsigned nib = bb >> (q4 * 4);
          float s1 = sqi2 + skv.x, l1 = fmaxf(s1, 0.01f * s1);
          float s2 = sqi2 + skv.y, l2 = fmaxf(s2, 0.01f * s2);
          float s3 = sqi2 + skv.z, l3 = fmaxf(s3, 0.01f * s3);
          float s4 = sqi2 + skv.w, l4 = fmaxf(s4, 0.01f * s4);
          zs += (nib & 1u) ? __expf(l1 - mx) : emx;
          zs += (nib & 2u) ? __expf(l2 - mx) : emx;
          zs += (nib & 4u) ? __expf(l3 - mx) : emx;
          zs += (nib & 8u) ? __expf(l4 - mx) : emx;
        }
      }
    } else {
      zs = 256.f * emx;
      if ((ig >> 8) == seg) {
        float s = sqi2 + sklds[ig & (kC - 1)];
        float lr = fmaxf(s, 0.01f * s);
        zs += __expf(lr - mx) - emx;
      }
    }
    #pragma unroll
    for (int d2 = 1; d2 < 8; d2 <<= 1) zs += __shfl_xor(zs, d2);
    if (seg == 0) { smx[rr] = mx; szv[rr] = 1.0f / zs; }
  }
  __syncthreads();

  int f = t >> 1, h = t & 1;
  int mt_b = f >> 6;
  int lb = f & 63;
  int irow_l = mt_b * 16 + (lb & 15);
  int quad_b = lb >> 4;
  int i_g = i0 + irow_l;
  float sqi = ssq[irow_l];
  float mri = smx[irow_l];
  int joff = quad_b * 8 + h * 4;
  bool irow_ok = (i_g < kN);
  const unsigned char* bitb = (const unsigned char*)bitlds + irow_l * 256;

  auto buildP = [&](int k0, int buf) {
    float4 skv = *(const float4*)(sklds + k0 + joff);
    unsigned byte;
    if (irow_ok) {
      byte = bitb[(k0 >> 3) + quad_b];
    } else {
      int d0 = i_g - (k0 + quad_b * 8);
      byte = ((unsigned)d0 < 8u) ? (1u << d0) : 0u;
    }
    unsigned nib = byte >> (h * 4);
    unsigned short us[4];
    float sv[4] = {skv.x, skv.y, skv.z, skv.w};
    #pragma unroll
    for (int dj = 0; dj < 4; ++dj) {
      float s = sqi + sv[dj];
      float lr = fmaxf(s, 0.01f * s);
      float val = ((nib >> dj) & 1u) ? lr : 0.f;
      us[dj] = f2bf_fast(__expf(val - mri));
    }
    uint2 pk;
    pk.x = us[0] | ((unsigned)us[1] << 16);
    pk.y = us[2] | ((unsigned)us[3] << 16);
    *(uint2*)(&pshare[buf][f * 8 + h * 4]) = pk;
  };

  f32x4 acc00 = {0.f, 0.f, 0.f, 0.f}, acc01 = acc00, acc10 = acc00, acc11 = acc00;
  int m = lane & 15, quad = lane >> 4;
  int nbase = w * 32;
  const unsigned short* vtb = Vt + (size_t)b * 262144;
  const unsigned short* p0 = vtb + (size_t)(w * 2) * 512 + lane * 8;
  const unsigned short* p1 = p0 + 512;

  buildP(0, 0);
  bfrag8 b0n = *(const bfrag8*)p0;
  bfrag8 b1n = *(const bfrag8*)p1;
  __syncthreads();

  for (int k0 = 0; k0 < kC; k0 += 32) {
    int cur = (k0 >> 5) & 1;
    bfrag8 bf0 = b0n, bf1 = b1n;
    if (k0 + 32 < kC) {
      size_t off = (size_t)((k0 >> 5) + 1) * 4096;
      b0n = *(const bfrag8*)(p0 + off);
      b1n = *(const bfrag8*)(p1 + off);
    }
    bfrag8 a0 = *(const bfrag8*)(&pshare[cur][(0 * 64 + lane) * 8]);
    bfrag8 a1 = *(const bfrag8*)(&pshare[cur][(1 * 64 + lane) * 8]);
    acc00 = mfma16(a0, bf0, acc00);
    acc01 = mfma16(a0, bf1, acc01);
    acc10 = mfma16(a1, bf0, acc10);
    acc11 = mfma16(a1, bf1, acc11);
    if (k0 + 32 < kC) buildP(k0 + 32, cur ^ 1);
    __syncthreads();
  }

  #pragma unroll
  for (int reg = 0; reg < 4; ++reg) {
    int il_a = quad * 4 + reg;
    int i_a = i0 + il_a;
    int i_b = i_a + 16;
    float za = szv[il_a];
    float zb = szv[il_a + 16];
    unsigned* oa = outw + ((size_t)b * kC + i_a) * kD + nbase + m;
    unsigned* ob = outw + ((size_t)b * kC + i_b) * kD + nbase + m;
    oa[0]  = pack2(acc00[reg] * za);
    oa[16] = pack2(acc01[reg] * za);
    ob[0]  = pack2(acc10[reg] * zb);
    ob[16] = pack2(acc11[reg] * zb);
  }
}

// ---------- K3: mix GEMM (K=256, 64-row tiles, packed IO); mode1 writes outputs ----------
__global__ __launch_bounds__(256) void k_mix64(Raw r, int l,
    const unsigned* __restrict__ seqb, const unsigned* __restrict__ attnw,
    const unsigned short* __restrict__ wt, const float* __restrict__ bmix,
    unsigned* __restrict__ featsOut, void* __restrict__ outx, float* __restrict__ part,
    int mode)
{
  __shared__ __align__(16) char smem[20480];
  unsigned short (*Ah)[64 * 40] = (unsigned short(*)[64 * 40])smem;
  unsigned short (*Al)[64 * 40] = (unsigned short(*)[64 * 40])(smem + 10240);
  constexpr int K = 256;
  int bid = blockIdx.x, t = threadIdx.x;
  int lane = t & 63, w = t >> 6, m = lane & 15, quad = lane >> 4;
  bool bf = sniff(r);
  int gr0 = bid * 64;
  int b = gr0 >> 11;
  int arow = t >> 2, kq = (t & 3) * 8;
  const unsigned* s0 = seqb  + (size_t)(gr0 + arow) * kD;
  const unsigned* s1 = attnw + (size_t)(gr0 + arow) * kD;
  const unsigned short* wth = wt + (size_t)l * WT_LS + WT_MIXH;
  const unsigned short* wtl = wt + (size_t)l * WT_LS + WT_MIXL;
  const unsigned short* pbh = wth + (size_t)(w * 2) * 512 + lane * 8;
  const unsigned short* pbl = wtl + (size_t)(w * 2) * 512 + lane * 8;

  auto build = [&](int kb, int buf) {
    int kg = kb + kq;
    const unsigned* sp = (kg < kD) ? (s0 + kg) : (s1 + kg - kD);
    uint4 v0 = *(const uint4*)sp;
    uint4 v1 = *(const uint4*)(sp + 4);
    uint4 ph, pl;
    ph.x = (v0.x >> 16) | (v0.y & 0xFFFF0000u);
    ph.y = (v0.z >> 16) | (v0.w & 0xFFFF0000u);
    ph.z = (v1.x >> 16) | (v1.y & 0xFFFF0000u);
    ph.w = (v1.z >> 16) | (v1.w & 0xFFFF0000u);
    pl.x = (v0.x & 0xFFFFu) | (v0.y << 16);
    pl.y = (v0.z & 0xFFFFu) | (v0.w << 16);
    pl.z = (v1.x & 0xFFFFu) | (v1.y << 16);
    pl.w = (v1.z & 0xFFFFu) | (v1.w << 16);
    *(uint4*)&Ah[buf][arow * 40 + kq] = ph;
    *(uint4*)&Al[buf][arow * 40 + kq] = pl;
  };

  f32x4 acc[4][2];
  #pragma unroll
  for (int mi = 0; mi < 4; ++mi) { acc[mi][0] = {0.f,0.f,0.f,0.f}; acc[mi][1] = {0.f,0.f,0.f,0.f}; }

  build(0, 0);
  __syncthreads();
  for (int kb = 0; kb < K; kb += 32) {
    int cur = (kb >> 5) & 1;
    int kc = kb >> 5;
    bfrag8 bh0 = *(const bfrag8*)(pbh + (size_t)kc * 4096);
    bfrag8 bh1 = *(const bfrag8*)(pbh + (size_t)kc * 4096 + 512);
    bfrag8 bl0 = {}, bl1 = {};
    if (!bf) {
      bl0 = *(const bfrag8*)(pbl + (size_t)kc * 4096);
      bl1 = *(const bfrag8*)(pbl + (size_t)kc * 4096 + 512);
    }
    if (kb + 32 < K) build(kb + 32, cur ^ 1);
    #pragma unroll
    for (int mi = 0; mi < 4; ++mi) {
      bfrag8 ah = *(const bfrag8*)&Ah[cur][(mi * 16 + m) * 40 + quad * 8];
      bfrag8 al = *(const bfrag8*)&Al[cur][(mi * 16 + m) * 40 + quad * 8];
      acc[mi][0] = mfma16(ah, bh0, acc[mi][0]);
      acc[mi][0] = mfma16(al, bh0, acc[mi][0]);
      acc[mi][1] = mfma16(ah, bh1, acc[mi][1]);
      acc[mi][1] = mfma16(al, bh1, acc[mi][1]);
      if (!bf) {
        acc[mi][0] = mfma16(ah, bl0, acc[mi][0]);
        acc[mi][1] = mfma16(ah, bl1, acc[mi][1]);
      }
    }
    __syncthreads();
  }

  int n0 = w * 32 + m;
  float bv0 = bmix[(size_t)l * kD + n0];
  float bv1 = bmix[(size_t)l * kD + n0 + 16];
  if (mode == 0) {
    #pragma unroll
    for (int mi = 0; mi < 4; ++mi)
      #pragma unroll
      for (int reg = 0; reg < 4; ++reg) {
        size_t row = (size_t)gr0 + mi * 16 + quad * 4 + reg;
        featsOut[row * kD + n0]      = pack2(acc[mi][0][reg] + bv0);
        featsOut[row * kD + n0 + 16] = pack2(acc[mi][1][reg] + bv1);
      }
  } else {
    float sum0 = 0.f, sum1 = 0.f;
    #pragma unroll
    for (int mi = 0; mi < 4; ++mi)
      #pragma unroll
      for (int reg = 0; reg < 4; ++reg) {
        size_t row = (size_t)gr0 + mi * 16 + quad * 4 + reg;
        float v0 = acc[mi][0][reg] + bv0;
        float v1 = acc[mi][1][reg] + bv1;
        if (bf) {
          unsigned short* o = (unsigned short*)outx + 1024;
          o[row * kD + n0]      = f2bf(v0);
          o[row * kD + n0 + 16] = f2bf(v1);
        } else {
          float* o = (float*)outx + 1024;
          o[row * kD + n0]      = v0;
          o[row * kD + n0 + 16] = v1;
        }
        sum0 += v0; sum1 += v1;
      }
    sum0 += __shfl_xor(sum0, 16); sum0 += __shfl_xor(sum0, 32);
    sum1 += __shfl_xor(sum1, 16); sum1 += __shfl_xor(sum1, 32);
    if (quad == 0) {
      atomicAdd(&part[(size_t)b * kD + n0],      sum0);
      atomicAdd(&part[(size_t)b * kD + n0 + 16], sum1);
    }
  }
}

// ---------- K4: final mean ----------
__global__ __launch_bounds__(128) void k_mean(Raw r, const float* __restrict__ part,
                                              void* __restrict__ out) {
  bool bf = sniff(r);
  int b = blockIdx.x, d = threadIdx.x;
  float v = part[(size_t)b * kD + d] * (1.0f / kC);
  if (bf) ((unsigned short*)out)[b * kD + d] = f2bf(v);
  else    ((float*)out)[b * kD + d] = v;
}

extern "C" void kernel_launch(void* const* d_in, const int* in_sizes, int n_in,
                              void* d_out, int out_size, void* d_ws, size_t ws_size,
                              hipStream_t stream) {
  Raw r;
  r.ops = d_in[0];  r.mask = d_in[1];
  r.rel = (const int*)d_in[2]; r.bidx = (const int*)d_in[3]; r.eidx = (const int*)d_in[4];
  r.ibw = d_in[5];  r.ibb = d_in[6];  r.iew = d_in[7];  r.ieb = d_in[8];
  r.bbw = d_in[9];  r.bbb = d_in[10]; r.bew = d_in[11]; r.beb = d_in[12];
  r.sw  = d_in[13]; r.sb  = d_in[14]; r.aw  = d_in[15]; r.ab  = d_in[16];
  r.scw = d_in[17]; r.scb = d_in[18]; r.aow = d_in[19]; r.aob = d_in[20];
  r.mw  = d_in[21]; r.mb  = d_in[22];

  float* ws = (float*)d_ws;
  unsigned* feats = (unsigned*)(ws + OF_FEATS);
  unsigned* seq   = (unsigned*)(ws + OF_SEQ);
  unsigned* attnw = (unsigned*)(ws + OF_ATTN);
  float* sq    = ws + OF_SQ;
  float* sk    = ws + OF_SK;
  float* u2    = ws + OF_U;
  float* part  = ws + OF_PART;
  float* bmix  = ws + OF_BMIX;
  unsigned short* wt = (unsigned short*)(ws + OF_WT);
  unsigned short* Vt = (unsigned short*)(ws + OF_V);
  unsigned*     bits = (unsigned*)(ws + OF_V + 1048576);

  k_prep<<<RP_TOT, 256, 0, stream>>>(r, feats, wt, bmix, u2, part);
  k_mask<<<kB * kN, 256, 0, stream>>>(r, bits);

  for (int l = 0; l < kL; ++l) {
    k_stage1<<<528, 256, 0, stream>>>(r, l, feats, wt, u2, seq, Vt, sq, sk);
    k_attn_pv_mfma<<<dim3(64, kB), 256, 0, stream>>>(bits, sq, sk, Vt, attnw);
    k_mix64<<<256, 256, 0, stream>>>(r, l, seq, attnw, wt, bmix, feats, d_out, part,
                                     (l == kL - 1) ? 1 : 0);
  }

  k_mean<<<kB, 128, 0, stream>>>(r, part, d_out);
}

// Round 12
// 463.265 us; speedup vs baseline: 1.2137x; 1.0149x over previous
//
#include <hip/hip_runtime.h>

// Problem constants
constexpr int kB = 8;
constexpr int kN = 2046;
constexpr int kC = 2048;   // kN + 2
constexpr int kD = 128;
constexpr int kJ = 128;
constexpr int kL = 2;

typedef short bfrag8 __attribute__((ext_vector_type(8)));
typedef float f32x4 __attribute__((ext_vector_type(4)));

// ---------- bf16 helpers ----------
__device__ __forceinline__ float bf2f(unsigned short h) {
  union { unsigned u; float f; } x; x.u = ((unsigned)h) << 16; return x.f;
}
__device__ __forceinline__ unsigned short f2bf(float f) {
  union { float f; unsigned u; } x; x.f = f;
  unsigned u = x.u;
  if ((u & 0x7fffffffu) > 0x7f800000u) return (unsigned short)((u >> 16) | 0x40);
  return (unsigned short)((u + 0x7fffu + ((u >> 16) & 1u)) >> 16);
}
__device__ __forceinline__ unsigned short f2bf_fast(float f) {  // finite inputs
  union { float f; unsigned u; } x; x.f = f;
  return (unsigned short)((x.u + 0x7fffu + ((x.u >> 16) & 1u)) >> 16);
}
__device__ __forceinline__ void split2(float x, unsigned short& h, unsigned short& l) {
  unsigned short hh = f2bf_fast(x);
  h = hh;
  l = f2bf_fast(x - bf2f(hh));
}

// ---------- raw input pointers ----------
struct Raw {
  const void *ops, *mask;
  const int *rel, *bidx, *eidx;
  const void *ibw, *ibb, *iew, *ieb;       // init begin/end proj
  const void *bbw, *bbb, *bew, *beb;       // per-layer begin/end proj
  const void *sw, *sb;                     // seq_mix
  const void *aw, *ab;                     // attn_w
  const void *scw, *scb;                   // score
  const void *aow, *aob;                   // attn_out
  const void *mw, *mb;                     // mix
};

__device__ __forceinline__ float rp(const void* p, size_t i, bool bf) {
  return bf ? bf2f(((const unsigned short*)p)[i]) : ((const float*)p)[i];
}

// per-wave dtype sniff over first 1024 words of operation_features
__device__ __forceinline__ bool sniff(const Raw& r) {
  const unsigned* x = (const unsigned*)r.ops;
  int lane = (int)(threadIdx.x & 63);
  int hits = 0;
  #pragma unroll
  for (int q = 0; q < 16; ++q) {
    unsigned w = x[q * 64 + lane];
    unsigned e0 = (w >> 7) & 0xFFu;
    hits += (e0 == 0u || (e0 >= 96u && e0 <= 134u)) ? 1 : 0;
  }
  #pragma unroll
  for (int o = 1; o < 64; o <<= 1) hits += __shfl_xor(hits, o);
  return hits >= 512;
}

// ---------- workspace layout (float offsets) ----------
constexpr size_t OF_FEATS = 0;                       // f32, 2097152
constexpr size_t OF_SEQ   = 2097152;
constexpr size_t OF_ATTN  = 4194304;
constexpr size_t OF_V     = 6291456;                 // VtF (1M floats) + bits (1M floats)
constexpr size_t OF_SQ    = 8388608;
constexpr size_t OF_SK    = 8404992;
constexpr size_t OF_U     = 8421376;
constexpr size_t OF_PART  = 8422400;
constexpr size_t OF_BMIX  = 8423424;
constexpr size_t OF_WT    = 8423680;                 // ushort arena

// Wt arena (ushort offsets), per-layer stride. Fragment layout:
// frag(kc, nt, lane, e): element (n = nt*16 + (lane&15), k = kc*32 + (lane>>4)*8 + e)
constexpr int WT_SEQH = 0;        // K=384
constexpr int WT_SEQL = 49152;
constexpr int WT_VH   = 98304;    // K=128
constexpr int WT_VL   = 114688;
constexpr int WT_MIXH = 131072;   // K=256
constexpr int WT_MIXL = 163840;
constexpr int WT_LS   = 196608;

// prep role boundaries (mask handled by k_mask; no bits-zero needed)
constexpr int RP_CAST = 4092;
constexpr int RP_WT   = RP_CAST + 640;   // 4732
constexpr int RP_WF   = RP_WT + 258;     // 4990
constexpr int RP_UV   = RP_WF + 2;       // 4992
constexpr int RP_BE   = RP_UV + 16;      // 5008
constexpr int RP_TOT  = RP_BE + 1;       // 5009 (zero part)

// ---------- MFMA helper ----------
__device__ __forceinline__ f32x4 mfma16(bfrag8 a, bfrag8 b, f32x4 c) {
  return __builtin_amdgcn_mfma_f32_16x16x32_bf16(a, b, c, 0, 0, 0);
}

// ---------- K0a: mask -> bits. One block per row; loads issued up-front, LDS assemble. ----------
__global__ __launch_bounds__(256) void k_mask(Raw r, unsigned* __restrict__ bits32) {
  __shared__ unsigned char sb[256];
  bool bf = sniff(r);
  int row = blockIdx.x;              // 0..B*kN-1
  int b = row / kN, i = row - b * kN;
  int t = threadIdx.x;
  unsigned bb = 0;
  if (bf) {
    const char* base = (const char*)r.mask + (size_t)row * (kN * 2);
    int off = (t < 255) ? (t * 16) : 4076;          // t=255 covers elems 2038..2045
    uint4 v = *(const uint4*)(base + off);
    unsigned u[4] = {v.x, v.y, v.z, v.w};
    #pragma unroll
    for (int k = 0; k < 8; ++k) {
      unsigned h = (u[k >> 1] >> ((k & 1) * 16)) & 0xFFFFu;
      bb |= (h != 0u) ? (1u << k) : 0u;
    }
  } else {
    const char* base = (const char*)r.mask + (size_t)row * (kN * 4);
    int off = (t < 255) ? (t * 32) : 8152;
    uint4 a = *(const uint4*)(base + off);
    uint4 c = *(const uint4*)(base + off + 16);
    unsigned u[8] = {a.x, a.y, a.z, a.w, c.x, c.y, c.z, c.w};
    #pragma unroll
    for (int k = 0; k < 8; ++k) bb |= (u[k] != 0u) ? (1u << k) : 0u;
  }
  sb[t] = (t < 255) ? (unsigned char)bb : (unsigned char)((bb >> 2) & 0x3Fu);
  __syncthreads();
  if (t < 64) {
    unsigned w = *(const unsigned*)(sb + 4 * t);
    bits32[((size_t)b * kC + i) * 64 + t] = w;
  }
}

// ---------- K0b: prep (cast, weights, fuse, uvec, init begin/end, zero part) ----------
__global__ __launch_bounds__(256) void k_prep(Raw r, float* __restrict__ feats,
                                              unsigned short* __restrict__ wt,
                                              float* __restrict__ bmix,
                                              float* __restrict__ u2,
                                              float* __restrict__ part) {
  __shared__ __align__(16) char smem[4096];
  int bid = blockIdx.x, t = threadIdx.x;
  bool bf = sniff(r);

  if (bid < RP_CAST) {
    // cast ops -> feats rows 0..N-1 (f32)
    int idx = bid * 256 + t;
    int elem = idx * 2;
    int b = elem / (kN * kD);
    int rr = elem - b * (kN * kD);
    float2 f;
    if (bf) {
      unsigned u = ((const unsigned*)r.ops)[idx];
      f.x = bf2f((unsigned short)(u & 0xffffu));
      f.y = bf2f((unsigned short)(u >> 16));
    } else {
      f = ((const float2*)r.ops)[idx];
    }
    *(float2*)(feats + (size_t)b * kC * kD + rr) = f;
  } else if (bid < RP_WT) {
    // transpose+split weights into fragment layout
    int idx = (bid - RP_CAST) * 256 + t;   // < 163840
    int l = idx / 81920;
    int rr = idx - l * 81920;
    const void* src; size_t si; int dH, dL, k, n;
    if (rr < 49152) {
      k = rr >> 7; n = rr & 127;
      src = r.sw; si = (size_t)l * 49152 + (size_t)k * 128 + n;
      dH = l * WT_LS + WT_SEQH; dL = l * WT_LS + WT_SEQL;
    } else if (rr < 65536) {
      int e = rr - 49152; k = e >> 7; n = e & 127;
      src = r.aw; si = (size_t)l * 49152 + (size_t)k * 384 + 256 + n;
      dH = l * WT_LS + WT_VH; dL = l * WT_LS + WT_VL;
    } else {
      int e = rr - 65536; k = e >> 7; n = e & 127;
      src = r.mw; si = (size_t)l * 32768 + (size_t)k * 128 + n;
      dH = l * WT_LS + WT_MIXH; dL = l * WT_LS + WT_MIXL;
    }
    float v = rp(src, si, bf);
    unsigned short h, lo;
    split2(v, h, lo);
    int kc = k >> 5, q = (k >> 3) & 3, e8 = k & 7;
    int fa = ((kc * 8 + (n >> 4)) * 64 + (q * 16 + (n & 15))) * 8 + e8;
    wt[dH + fa] = h;
    wt[dL + fa] = lo;
  } else if (bid < RP_WF) {
    // fuse ao_w @ mix_bot -> mix fragments k in [128,256)
    int rb = bid - RP_WT;
    int l = rb / 129, d1 = rb - l * 129;
    if (t < 128) {
      int d = t;
      size_t mixbot = (size_t)l * 32768 + 16384;
      if (d1 < 128) {
        float acc = 0.f;
        for (int d2 = 0; d2 < kD; ++d2)
          acc += rp(r.aow, (size_t)l * 16384 + (size_t)d1 * 128 + d2, bf)
               * rp(r.mw, mixbot + (size_t)d2 * 128 + d, bf);
        unsigned short h, lo;
        split2(acc, h, lo);
        int k = 128 + d1;
        int kc = k >> 5, q = (k >> 3) & 3, e8 = k & 7;
        int fa = ((kc * 8 + (d >> 4)) * 64 + (q * 16 + (d & 15))) * 8 + e8;
        wt[l * WT_LS + WT_MIXH + fa] = h;
        wt[l * WT_LS + WT_MIXL + fa] = lo;
      } else {
        float acc = rp(r.mb, (size_t)l * 128 + d, bf);
        for (int d2 = 0; d2 < kD; ++d2)
          acc += rp(r.aob, (size_t)l * 128 + d2, bf)
               * rp(r.mw, mixbot + (size_t)d2 * 128 + d, bf);
        bmix[(size_t)l * kD + d] = acc;
      }
    }
  } else if (bid < RP_UV) {
    // u-vectors
    int l = bid - RP_WF;
    float* swm = (float*)smem;
    float* red = (float*)smem + 256;
    if (t < 128) {
      swm[t]       = rp(r.scw, (size_t)l * 256 + t, bf);
      swm[128 + t] = rp(r.scw, (size_t)l * 256 + 128 + t, bf);
    }
    __syncthreads();
    if (t < 128) {
      int k = t;
      size_t base = (size_t)l * 49152 + (size_t)k * 384;
      float uq = 0.f, uk = 0.f;
      for (int d2 = 0; d2 < kD; ++d2) {
        uq += rp(r.aw, base + d2, bf) * swm[d2];
        uk += rp(r.aw, base + 128 + d2, bf) * swm[128 + d2];
      }
      float* u = u2 + (size_t)l * 272;
      u[k] = uq; u[128 + k] = uk;
      red[k] = rp(r.ab, (size_t)l * 384 + k, bf) * swm[k]
             + rp(r.ab, (size_t)l * 384 + 128 + k, bf) * swm[128 + k];
    }
    __syncthreads();
    if (t == 0) {
      float s = rp(r.scb, l, bf);
      for (int i = 0; i < 128; ++i) s += red[i];
      u2[(size_t)l * 272 + 256] = s;
    }
  } else if (bid < RP_BE) {
    // init begin/end
    int rb = bid - RP_UV;
    int b = rb >> 1, sel = rb & 1;
    float* msh = (float*)smem;
    const int* idx = (sel ? r.eidx : r.bidx) + b * kJ;
    const void* wv = sel ? r.iew : r.ibw;
    const void* bb = sel ? r.ieb : r.ibb;
    if (t < 128) {
      int d = t;
      float acc = 0.f;
      for (int j = 0; j < kJ; ++j)
        acc += rp(r.ops, ((size_t)b * kN + idx[j]) * kD + d, bf);
      msh[d] = acc * (1.0f / kJ);
    }
    __syncthreads();
    if (t < 128) {
      int d = t;
      float o = rp(bb, d, bf);
      for (int k = 0; k < kD; ++k) o += msh[k] * rp(wv, (size_t)k * kD + d, bf);
      feats[(size_t)b * kC * kD + (size_t)(kN + sel) * kD + d] = o;
    }
  } else {
    #pragma unroll
    for (int q = 0; q < 4; ++q) part[q * 256 + t] = 0.f;
  }
}

// ---------- K1: stage1 — seq GEMM + vproj GEMM + layer begin/end ----------
__global__ __launch_bounds__(256) void k_stage1(Raw r, int l,
    const float* __restrict__ feats, const unsigned short* __restrict__ wt,
    const float* __restrict__ u2, float* __restrict__ seq,
    unsigned short* __restrict__ Vt, float* __restrict__ sq, float* __restrict__ sk)
{
  __shared__ __align__(16) char smem[21504];
  unsigned short (*Ah)[64 * 40] = (unsigned short(*)[64 * 40])smem;
  unsigned short (*Al)[64 * 40] = (unsigned short(*)[64 * 40])(smem + 10240);
  float* su = (float*)(smem + 20480);
  int bid = blockIdx.x, t = threadIdx.x;
  int lane = t & 63, w = t >> 6, m = lane & 15, quad = lane >> 4;
  bool bf = sniff(r);
  const unsigned short* wl = wt + (size_t)l * WT_LS;

  if (bid < 512) {
    bool isv = bid >= 256;
    int rb = isv ? bid - 256 : bid;
    int gr0 = rb * 64;
    int b = gr0 >> 11, r0 = gr0 & 2047;
    int arow = t >> 2, kq = (t & 3) * 8;
    int nl = r0 + arow;
    const float* fb = feats + (size_t)b * kC * kD;
    const float *s0, *s1, *s2;
    if (!isv) {
      int nr = (nl <= kN - 1) ? nl : (kN - 1);
      const int* rel = r.rel + ((size_t)b * kN + nr) * 2;
      int rpd = rel[0], rsc = rel[1];
      int p = (rpd < 0) ? kN : rpd;
      int s = (rsc < 0) ? (kN + 1) : rsc;
      s0 = fb + (size_t)nl * kD;
      s1 = fb + (size_t)p * kD;
      s2 = fb + (size_t)s * kD;
    } else {
      s0 = fb + (size_t)nl * kD; s1 = s0; s2 = s0;
      su[t] = u2[(size_t)l * 272 + t];
    }
    const int K = isv ? 128 : 384;
    const unsigned short* wth = isv ? (wl + WT_VH) : (wl + WT_SEQH);
    const unsigned short* wtl = isv ? (wl + WT_VL) : (wl + WT_SEQL);
    const unsigned short* pbh = wth + (size_t)(w * 2) * 512 + lane * 8;
    const unsigned short* pbl = wtl + (size_t)(w * 2) * 512 + lane * 8;
    float pq = 0.f, pk2 = 0.f;

    auto build = [&](int kb, int buf) {
      int kg = kb + kq;
      const float* sp;
      if (!isv) sp = (kg < 128) ? (s0 + kg) : (kg < 256) ? (s1 + kg - 128) : (s2 + kg - 256);
      else      sp = s0 + kg;
      float4 xa = *(const float4*)sp;
      float4 xb = *(const float4*)(sp + 4);
      if (isv) {
        pq  += xa.x * su[kg]     + xa.y * su[kg + 1] + xa.z * su[kg + 2] + xa.w * su[kg + 3]
             + xb.x * su[kg + 4] + xb.y * su[kg + 5] + xb.z * su[kg + 6] + xb.w * su[kg + 7];
        pk2 += xa.x * su[128 + kg]     + xa.y * su[128 + kg + 1] + xa.z * su[128 + kg + 2] + xa.w * su[128 + kg + 3]
             + xb.x * su[128 + kg + 4] + xb.y * su[128 + kg + 5] + xb.z * su[128 + kg + 6] + xb.w * su[128 + kg + 7];
      }
      unsigned short h[8], lo[8];
      split2(xa.x, h[0], lo[0]); split2(xa.y, h[1], lo[1]);
      split2(xa.z, h[2], lo[2]); split2(xa.w, h[3], lo[3]);
      split2(xb.x, h[4], lo[4]); split2(xb.y, h[5], lo[5]);
      split2(xb.z, h[6], lo[6]); split2(xb.w, h[7], lo[7]);
      uint4 ph, pl;
      ph.x = h[0] | ((unsigned)h[1] << 16);  ph.y = h[2] | ((unsigned)h[3] << 16);
      ph.z = h[4] | ((unsigned)h[5] << 16);  ph.w = h[6] | ((unsigned)h[7] << 16);
      pl.x = lo[0] | ((unsigned)lo[1] << 16); pl.y = lo[2] | ((unsigned)lo[3] << 16);
      pl.z = lo[4] | ((unsigned)lo[5] << 16); pl.w = lo[6] | ((unsigned)lo[7] << 16);
      *(uint4*)&Ah[buf][arow * 40 + kq] = ph;
      *(uint4*)&Al[buf][arow * 40 + kq] = pl;
    };

    f32x4 acc[4][2];
    #pragma unroll
    for (int mi = 0; mi < 4; ++mi) { acc[mi][0] = {0.f,0.f,0.f,0.f}; acc[mi][1] = {0.f,0.f,0.f,0.f}; }

    __syncthreads();   // su visible
    build(0, 0);
    __syncthreads();
    for (int kb = 0; kb < K; kb += 32) {
      int cur = (kb >> 5) & 1;
      int kc = kb >> 5;
      bfrag8 bh0 = *(const bfrag8*)(pbh + (size_t)kc * 4096);
      bfrag8 bh1 = *(const bfrag8*)(pbh + (size_t)kc * 4096 + 512);
      bfrag8 bl0 = {}, bl1 = {};
      if (!bf) {
        bl0 = *(const bfrag8*)(pbl + (size_t)kc * 4096);
        bl1 = *(const bfrag8*)(pbl + (size_t)kc * 4096 + 512);
      }
      if (kb + 32 < K) build(kb + 32, cur ^ 1);
      #pragma unroll
      for (int mi = 0; mi < 4; ++mi) {
        bfrag8 ah = *(const bfrag8*)&Ah[cur][(mi * 16 + m) * 40 + quad * 8];
        bfrag8 al = *(const bfrag8*)&Al[cur][(mi * 16 + m) * 40 + quad * 8];
        acc[mi][0] = mfma16(ah, bh0, acc[mi][0]);
        acc[mi][0] = mfma16(al, bh0, acc[mi][0]);
        acc[mi][1] = mfma16(ah, bh1, acc[mi][1]);
        acc[mi][1] = mfma16(al, bh1, acc[mi][1]);
        if (!bf) {
          acc[mi][0] = mfma16(ah, bl0, acc[mi][0]);
          acc[mi][1] = mfma16(ah, bl1, acc[mi][1]);
        }
      }
      __syncthreads();
    }

    int n0 = w * 32 + m;
    if (!isv) {
      float bv0 = rp(r.sb, (size_t)l * 128 + n0, bf);
      float bv1 = rp(r.sb, (size_t)l * 128 + n0 + 16, bf);
      #pragma unroll
      for (int mi = 0; mi < 4; ++mi)
        #pragma unroll
        for (int reg = 0; reg < 4; ++reg) {
          int ra = r0 + mi * 16 + quad * 4 + reg;
          if (ra < kN) {
            seq[((size_t)b * kC + ra) * kD + n0]      = acc[mi][0][reg] + bv0;
            seq[((size_t)b * kC + ra) * kD + n0 + 16] = acc[mi][1][reg] + bv1;
          }
        }
    } else {
      float bv0 = rp(r.ab, (size_t)l * 384 + 256 + n0, bf);
      float bv1 = rp(r.ab, (size_t)l * 384 + 256 + n0 + 16, bf);
      unsigned short* vtb = Vt + (size_t)b * 262144;
      #pragma unroll
      for (int mi = 0; mi < 4; ++mi)
        #pragma unroll
        for (int reg = 0; reg < 4; ++reg) {
          int c = r0 + mi * 16 + quad * 4 + reg;
          int kc = c >> 5, cq = (c >> 3) & 3, e8 = c & 7;
          int lp = cq * 16 + m;
          vtb[((kc * 8 + w * 2) * 64 + lp) * 8 + e8]       = f2bf_fast(acc[mi][0][reg] + bv0);
          vtb[((kc * 8 + w * 2 + 1) * 64 + lp) * 8 + e8]   = f2bf_fast(acc[mi][1][reg] + bv1);
        }
      pq  += __shfl_xor(pq, 1);  pq  += __shfl_xor(pq, 2);
      pk2 += __shfl_xor(pk2, 1); pk2 += __shfl_xor(pk2, 2);
      if ((t & 3) == 0) {
        sq[(size_t)b * kC + nl] = pq + u2[(size_t)l * 272 + 256];
        sk[(size_t)b * kC + nl] = pk2;
      }
    }
  } else {
    // layer begin/end: reads feats, writes seq rows N, N+1
    int rb = bid - 512;
    int b = rb >> 1, sel = rb & 1;
    float* msh = (float*)smem;
    const int* idx = (sel ? r.eidx : r.bidx) + b * kJ;
    const void* wv = sel ? r.bew : r.bbw;
    const void* bb = sel ? r.beb : r.bbb;
    size_t wbase = (size_t)l * kD * kD, bbase = (size_t)l * kD;
    if (t < 128) {
      int d = t;
      const float* fb2 = feats + (size_t)b * kC * kD;
      float acc = 0.f;
      for (int j = 0; j < kJ; ++j) acc += fb2[(size_t)idx[j] * kD + d];
      msh[d] = acc * (1.0f / kJ);
    }
    __syncthreads();
    if (t < 128) {
      int d = t;
      float o = rp(bb, bbase + d, bf);
      for (int k = 0; k < kD; ++k) o += msh[k] * rp(wv, wbase + (size_t)k * kD + d, bf);
      seq[(size_t)b * kC * kD + (size_t)(kN + sel) * kD + d] = o;
    }
  }
}

// ---------- K2: MFMA PV with fused softmax stats ----------
__global__ __launch_bounds__(256) void k_attn_pv_mfma(
    const unsigned* __restrict__ bits,
    const float* __restrict__ sq, const float* __restrict__ sk,
    const unsigned short* __restrict__ Vt,     // fragment layout per batch
    float* __restrict__ outw)
{
  int b = blockIdx.y;
  int i0 = blockIdx.x * 32;
  int t = threadIdx.x, lane = t & 63, w = t >> 6;

  __shared__ unsigned short pshare[2][1024];
  __shared__ float sklds[kC];
  __shared__ unsigned bitlds[2048];
  __shared__ float ssq[32], smx[32], szv[32];

  const float* skb = sk + (size_t)b * kC;
  #pragma unroll
  for (int q = 0; q < 8; ++q) sklds[q * 256 + t] = skb[q * 256 + t];
  const unsigned* bitrow = bits + ((size_t)b * kC + i0) * 64;
  #pragma unroll
  for (int q = 0; q < 8; ++q) bitlds[q * 256 + t] = bitrow[q * 256 + t];
  if (t < 32) ssq[t] = sq[(size_t)b * kC + i0 + t];
  __syncthreads();

  {
    int rr = t >> 3, seg = t & 7;
    int ig = i0 + rr;
    bool ok = (ig < kN);
    float sqi2 = ssq[rr];
    const unsigned* bw = bitlds + rr * 64 + seg * 8;
    const float* sks = sklds + seg * 256;
    float mx;
    if (ok) {
      float msk = -3e38f;
      #pragma unroll 1
      for (int w8 = 0; w8 < 8; ++w8) {
        unsigned bb = bw[w8];
        #pragma unroll
        for (int q4 = 0; q4 < 8; ++q4) {
          float4 skv = *(const float4*)(sks + w8 * 32 + q4 * 4);
          unsigned nib = bb >> (q4 * 4);
          msk = (nib & 1u) ? fmaxf(msk, skv.x) : msk;
          msk = (nib & 2u) ? fmaxf(msk, skv.y) : msk;
          msk = (nib & 4u) ? fmaxf(msk, skv.z) : msk;
          msk = (nib & 8u) ? fmaxf(msk, skv.w) : msk;
        }
      }
      #pragma unroll
      for (int d2 = 1; d2 < 8; d2 <<= 1) msk = fmaxf(msk, __shfl_xor(msk, d2));
      float s = sqi2 + msk;
      mx = fmaxf(0.f, fmaxf(s, 0.01f * s));
    } else {
      float s = sqi2 + sklds[ig & (kC - 1)];
      mx = fmaxf(0.f, fmaxf(s, 0.01f * s));
    }
    float emx = __expf(-mx);
    float zs = 0.f;
    if (ok) {
      #pragma unroll 1
      for (int w8 = 0; w8 < 8; ++w8) {
        unsigned bb = bw[w8];
        #pragma unroll
        for (int q4 = 0; q4 < 8; ++q4) {
          float4 skv = *(const float4*)(sks + w8 * 32 + q4 * 4);
          unsigned nib = bb >> (q4 * 4);
          float s1 = sqi2 + skv.x, l1 = fmaxf(s1, 0.01f * s1);
          float s2 = sqi2 + skv.y, l2 = fmaxf(s2, 0.01f * s2);
          float s3 = sqi2 + skv.z, l3 = fmaxf(s3, 0.01f * s3);
          float s4 = sqi2 + skv.w, l4 = fmaxf(s4, 0.01f * s4);
          zs += (nib & 1u) ? __expf(l1 - mx) : emx;
          zs += (nib & 2u) ? __expf(l2 - mx) : emx;
          zs += (nib & 4u) ? __expf(l3 - mx) : emx;
          zs += (nib & 8u) ? __expf(l4 - mx) : emx;
        }
      }
    } else {
      zs = 256.f * emx;
      if ((ig >> 8) == seg) {
        float s = sqi2 + sklds[ig & (kC - 1)];
        float lr = fmaxf(s, 0.01f * s);
        zs += __expf(lr - mx) - emx;
      }
    }
    #pragma unroll
    for (int d2 = 1; d2 < 8; d2 <<= 1) zs += __shfl_xor(zs, d2);
    if (seg == 0) { smx[rr] = mx; szv[rr] = 1.0f / zs; }
  }
  __syncthreads();

  int f = t >> 1, h = t & 1;
  int mt_b = f >> 6;
  int lb = f & 63;
  int irow_l = mt_b * 16 + (lb & 15);
  int quad_b = lb >> 4;
  int i_g = i0 + irow_l;
  float sqi = ssq[irow_l];
  float mri = smx[irow_l];
  int joff = quad_b * 8 + h * 4;
  bool irow_ok = (i_g < kN);
  const unsigned char* bitb = (const unsigned char*)bitlds + irow_l * 256;

  auto buildP = [&](int k0, int buf) {
    float4 skv = *(const float4*)(sklds + k0 + joff);
    unsigned byte;
    if (irow_ok) {
      byte = bitb[(k0 >> 3) + quad_b];
    } else {
      int d0 = i_g - (k0 + quad_b * 8);
      byte = ((unsigned)d0 < 8u) ? (1u << d0) : 0u;
    }
    unsigned nib = byte >> (h * 4);
    unsigned short us[4];
    float sv[4] = {skv.x, skv.y, skv.z, skv.w};
    #pragma unroll
    for (int dj = 0; dj < 4; ++dj) {
      float s = sqi + sv[dj];
      float lr = fmaxf(s, 0.01f * s);
      float val = ((nib >> dj) & 1u) ? lr : 0.f;
      us[dj] = f2bf_fast(__expf(val - mri));
    }
    uint2 pk;
    pk.x = us[0] | ((unsigned)us[1] << 16);
    pk.y = us[2] | ((unsigned)us[3] << 16);
    *(uint2*)(&pshare[buf][f * 8 + h * 4]) = pk;
  };

  f32x4 acc00 = {0.f, 0.f, 0.f, 0.f}, acc01 = acc00, acc10 = acc00, acc11 = acc00;
  int m = lane & 15, quad = lane >> 4;
  int nbase = w * 32;
  const unsigned short* vtb = Vt + (size_t)b * 262144;
  const unsigned short* p0 = vtb + (size_t)(w * 2) * 512 + lane * 8;
  const unsigned short* p1 = p0 + 512;

  buildP(0, 0);
  bfrag8 b0n = *(const bfrag8*)p0;
  bfrag8 b1n = *(const bfrag8*)p1;
  __syncthreads();

  for (int k0 = 0; k0 < kC; k0 += 32) {
    int cur = (k0 >> 5) & 1;
    bfrag8 bf0 = b0n, bf1 = b1n;
    if (k0 + 32 < kC) {
      size_t off = (size_t)((k0 >> 5) + 1) * 4096;
      b0n = *(const bfrag8*)(p0 + off);
      b1n = *(const bfrag8*)(p1 + off);
    }
    bfrag8 a0 = *(const bfrag8*)(&pshare[cur][(0 * 64 + lane) * 8]);
    bfrag8 a1 = *(const bfrag8*)(&pshare[cur][(1 * 64 + lane) * 8]);
    acc00 = mfma16(a0, bf0, acc00);
    acc01 = mfma16(a0, bf1, acc01);
    acc10 = mfma16(a1, bf0, acc10);
    acc11 = mfma16(a1, bf1, acc11);
    if (k0 + 32 < kC) buildP(k0 + 32, cur ^ 1);
    __syncthreads();
  }

  #pragma unroll
  for (int reg = 0; reg < 4; ++reg) {
    int il_a = quad * 4 + reg;
    int i_a = i0 + il_a;
    int i_b = i_a + 16;
    float za = szv[il_a];
    float zb = szv[il_a + 16];
    float* oa = outw + ((size_t)b * kC + i_a) * kD + nbase + m;
    float* ob = outw + ((size_t)b * kC + i_b) * kD + nbase + m;
    oa[0]  = acc00[reg] * za;
    oa[16] = acc01[reg] * za;
    ob[0]  = acc10[reg] * zb;
    ob[16] = acc11[reg] * zb;
  }
}

// ---------- K3: mix GEMM (K=256, 64-row tiles); mode1 writes outputs ----------
__global__ __launch_bounds__(256) void k_mix64(Raw r, int l,
    const float* __restrict__ seqb, const float* __restrict__ attnw,
    const unsigned short* __restrict__ wt, const float* __restrict__ bmix,
    float* __restrict__ featsOut, void* __restrict__ outx, float* __restrict__ part,
    int mode)
{
  __shared__ __align__(16) char smem[20480];
  unsigned short (*Ah)[64 * 40] = (unsigned short(*)[64 * 40])smem;
  unsigned short (*Al)[64 * 40] = (unsigned short(*)[64 * 40])(smem + 10240);
  constexpr int K = 256;
  int bid = blockIdx.x, t = threadIdx.x;
  int lane = t & 63, w = t >> 6, m = lane & 15, quad = lane >> 4;
  bool bf = sniff(r);
  int gr0 = bid * 64;
  int b = gr0 >> 11;
  int arow = t >> 2, kq = (t & 3) * 8;
  const float* s0 = seqb  + (size_t)(gr0 + arow) * kD;
  const float* s1 = attnw + (size_t)(gr0 + arow) * kD;
  const unsigned short* wth = wt + (size_t)l * WT_LS + WT_MIXH;
  const unsigned short* wtl = wt + (size_t)l * WT_LS + WT_MIXL;
  const unsigned short* pbh = wth + (size_t)(w * 2) * 512 + lane * 8;
  const unsigned short* pbl = wtl + (size_t)(w * 2) * 512 + lane * 8;

  auto build = [&](int kb, int buf) {
    int kg = kb + kq;
    const float* sp = (kg < kD) ? (s0 + kg) : (s1 + kg - kD);
    float4 xa = *(const float4*)sp;
    float4 xb = *(const float4*)(sp + 4);
    unsigned short h[8], lo[8];
    split2(xa.x, h[0], lo[0]); split2(xa.y, h[1], lo[1]);
    split2(xa.z, h[2], lo[2]); split2(xa.w, h[3], lo[3]);
    split2(xb.x, h[4], lo[4]); split2(xb.y, h[5], lo[5]);
    split2(xb.z, h[6], lo[6]); split2(xb.w, h[7], lo[7]);
    uint4 ph, pl;
    ph.x = h[0] | ((unsigned)h[1] << 16);  ph.y = h[2] | ((unsigned)h[3] << 16);
    ph.z = h[4] | ((unsigned)h[5] << 16);  ph.w = h[6] | ((unsigned)h[7] << 16);
    pl.x = lo[0] | ((unsigned)lo[1] << 16); pl.y = lo[2] | ((unsigned)lo[3] << 16);
    pl.z = lo[4] | ((unsigned)lo[5] << 16); pl.w = lo[6] | ((unsigned)lo[7] << 16);
    *(uint4*)&Ah[buf][arow * 40 + kq] = ph;
    *(uint4*)&Al[buf][arow * 40 + kq] = pl;
  };

  f32x4 acc[4][2];
  #pragma unroll
  for (int mi = 0; mi < 4; ++mi) { acc[mi][0] = {0.f,0.f,0.f,0.f}; acc[mi][1] = {0.f,0.f,0.f,0.f}; }

  build(0, 0);
  __syncthreads();
  for (int kb = 0; kb < K; kb += 32) {
    int cur = (kb >> 5) & 1;
    int kc = kb >> 5;
    bfrag8 bh0 = *(const bfrag8*)(pbh + (size_t)kc * 4096);
    bfrag8 bh1 = *(const bfrag8*)(pbh + (size_t)kc * 4096 + 512);
    bfrag8 bl0 = {}, bl1 = {};
    if (!bf) {
      bl0 = *(const bfrag8*)(pbl + (size_t)kc * 4096);
      bl1 = *(const bfrag8*)(pbl + (size_t)kc * 4096 + 512);
    }
    if (kb + 32 < K) build(kb + 32, cur ^ 1);
    #pragma unroll
    for (int mi = 0; mi < 4; ++mi) {
      bfrag8 ah = *(const bfrag8*)&Ah[cur][(mi * 16 + m) * 40 + quad * 8];
      bfrag8 al = *(const bfrag8*)&Al[cur][(mi * 16 + m) * 40 + quad * 8];
      acc[mi][0] = mfma16(ah, bh0, acc[mi][0]);
      acc[mi][0] = mfma16(al, bh0, acc[mi][0]);
      acc[mi][1] = mfma16(ah, bh1, acc[mi][1]);
      acc[mi][1] = mfma16(al, bh1, acc[mi][1]);
      if (!bf) {
        acc[mi][0] = mfma16(ah, bl0, acc[mi][0]);
        acc[mi][1] = mfma16(ah, bl1, acc[mi][1]);
      }
    }
    __syncthreads();
  }

  int n0 = w * 32 + m;
  float bv0 = bmix[(size_t)l * kD + n0];
  float bv1 = bmix[(size_t)l * kD + n0 + 16];
  if (mode == 0) {
    #pragma unroll
    for (int mi = 0; mi < 4; ++mi)
      #pragma unroll
      for (int reg = 0; reg < 4; ++reg) {
        size_t row = (size_t)gr0 + mi * 16 + quad * 4 + reg;
        featsOut[row * kD + n0]      = acc[mi][0][reg] + bv0;
        featsOut[row * kD + n0 + 16] = acc[mi][1][reg] + bv1;
      }
  } else {
    float sum0 = 0.f, sum1 = 0.f;
    #pragma unroll
    for (int mi = 0; mi < 4; ++mi)
      #pragma unroll
      for (int reg = 0; reg < 4; ++reg) {
        size_t row = (size_t)gr0 + mi * 16 + quad * 4 + reg;
        float v0 = acc[mi][0][reg] + bv0;
        float v1 = acc[mi][1][reg] + bv1;
        if (bf) {
          unsigned short* o = (unsigned short*)outx + 1024;
          o[row * kD + n0]      = f2bf(v0);
          o[row * kD + n0 + 16] = f2bf(v1);
        } else {
          float* o = (float*)outx + 1024;
          o[row * kD + n0]      = v0;
          o[row * kD + n0 + 16] = v1;
        }
        sum0 += v0; sum1 += v1;
      }
    sum0 += __shfl_xor(sum0, 16); sum0 += __shfl_xor(sum0, 32);
    sum1 += __shfl_xor(sum1, 16); sum1 += __shfl_xor(sum1, 32);
    if (quad == 0) {
      atomicAdd(&part[(size_t)b * kD + n0],      sum0);
      atomicAdd(&part[(size_t)b * kD + n0 + 16], sum1);
    }
  }
}

// ---------- K4: final mean ----------
__global__ __launch_bounds__(128) void k_mean(Raw r, const float* __restrict__ part,
                                              void* __restrict__ out) {
  bool bf = sniff(r);
  int b = blockIdx.x, d = threadIdx.x;
  float v = part[(size_t)b * kD + d] * (1.0f / kC);
  if (bf) ((unsigned short*)out)[b * kD + d] = f2bf(v);
  else    ((float*)out)[b * kD + d] = v;
}

extern "C" void kernel_launch(void* const* d_in, const int* in_sizes, int n_in,
                              void* d_out, int out_size, void* d_ws, size_t ws_size,
                              hipStream_t stream) {
  Raw r;
  r.ops = d_in[0];  r.mask = d_in[1];
  r.rel = (const int*)d_in[2]; r.bidx = (const int*)d_in[3]; r.eidx = (const int*)d_in[4];
  r.ibw = d_in[5];  r.ibb = d_in[6];  r.iew = d_in[7];  r.ieb = d_in[8];
  r.bbw = d_in[9];  r.bbb = d_in[10]; r.bew = d_in[11]; r.beb = d_in[12];
  r.sw  = d_in[13]; r.sb  = d_in[14]; r.aw  = d_in[15]; r.ab  = d_in[16];
  r.scw = d_in[17]; r.scb = d_in[18]; r.aow = d_in[19]; r.aob = d_in[20];
  r.mw  = d_in[21]; r.mb  = d_in[22];

  float* ws    = (float*)d_ws;
  float* feats = ws + OF_FEATS;
  float* seq   = ws + OF_SEQ;
  float* attnw = ws + OF_ATTN;
  float* sq    = ws + OF_SQ;
  float* sk    = ws + OF_SK;
  float* u2    = ws + OF_U;
  float* part  = ws + OF_PART;
  float* bmix  = ws + OF_BMIX;
  unsigned short* wt = (unsigned short*)(ws + OF_WT);
  unsigned short* Vt = (unsigned short*)(ws + OF_V);
  unsigned*     bits = (unsigned*)(ws + OF_V + 1048576);

  k_prep<<<RP_TOT, 256, 0, stream>>>(r, feats, wt, bmix, u2, part);
  k_mask<<<kB * kN, 256, 0, stream>>>(r, bits);

  for (int l = 0; l < kL; ++l) {
    k_stage1<<<528, 256, 0, stream>>>(r, l, feats, wt, u2, seq, Vt, sq, sk);
    k_attn_pv_mfma<<<dim3(64, kB), 256, 0, stream>>>(bits, sq, sk, Vt, attnw);
    k_mix64<<<256, 256, 0, stream>>>(r, l, seq, attnw, wt, bmix, feats, d_out, part,
                                     (l == kL - 1) ? 1 : 0);
  }

  k_mean<<<kB, 128, 0, stream>>>(r, part, d_out);
}